// Round 5
// baseline (2857.076 us; speedup 1.0000x reference)
//
#include <hip/hip_runtime.h>
#include <hip/hip_cooperative_groups.h>

namespace cg = cooperative_groups;

typedef _Float16 h16;
typedef _Float16 h16x8 __attribute__((ext_vector_type(8)));
typedef short short8 __attribute__((ext_vector_type(8)));
typedef float f32x4 __attribute__((ext_vector_type(4)));

// ---------- bf16 helpers (bit-level) ----------
__device__ __forceinline__ float bf2f(unsigned short u) {
    return __uint_as_float(((unsigned)u) << 16);
}
__device__ __forceinline__ unsigned short f2bf(float f) {
    unsigned x = __float_as_uint(f);
    unsigned r = x + 0x7fffu + ((x >> 16) & 1u);   // round-to-nearest-even
    return (unsigned short)(r >> 16);
}
__device__ __forceinline__ float gelu_fast(float v) {
    float y = 0.7978845608f * (v + 0.044715f * v * v * v);
    float e = __expf(2.0f * y);
    float th = 1.0f - 2.0f * __builtin_amdgcn_rcpf(e + 1.0f);
    return 0.5f * v * (1.0f + th);
}

// flag-aware input load: isbf=1 -> buffer holds bf16, else fp32. i = element idx.
__device__ __forceinline__ float ldin(const void* p, size_t i, int isbf) {
    return isbf ? bf2f(((const unsigned short*)p)[i]) : ((const float*)p)[i];
}

#define LN_EPS 1e-5f
#define NBMAX 256
#define NBLK 1024

// ---------- 0b. one-time weight transpose into MFMA frag layout ----------
// Derives dtype flag itself (writes it for k_in/k_fin).
// vecs layout (floats): [0:64) b1 | [64:128) g1 | [128:192) be1
//                       [192:384) bc for j=6,8,10 | [384:424) b2
__global__ void k_prep(const void* __restrict__ W1, const void* __restrict__ b1,
                       const void* __restrict__ g1, const void* __restrict__ be1,
                       const void* __restrict__ Wc, const void* __restrict__ bc,
                       const void* __restrict__ W2, const void* __restrict__ b2,
                       const void* __restrict__ g2, const void* __restrict__ be2,
                       int* __restrict__ flag,
                       short* __restrict__ W1f, h16* __restrict__ Wcf,
                       h16* __restrict__ W2f, float* __restrict__ vecs,
                       float2* __restrict__ GBv) {
    int isbf = (((const unsigned*)g1)[0] == 0x3F803F80u) ? 1 : 0;
    int t = threadIdx.x, b = blockIdx.x;
    if (b == 0) {                              // W1f: bf16 [4][4][64][8]
        for (int idx = t; idx < 1024; idx += 256) {
            int c = idx >> 8, tt = (idx >> 6) & 3, ln = idx & 63;
            int quad = ln >> 4, col = tt * 16 + (ln & 15);
#pragma unroll
            for (int j = 0; j < 8; j++) {
                int k = c * 32 + quad * 8 + j;
                W1f[idx * 8 + j] = (short)f2bf(ldin(W1, (size_t)k * 64 + col, isbf));
            }
        }
    } else if (b <= 3) {                       // Wcf[s]: f16 [2][4][64][8], s=0,1,2 -> j=6,8,10
        int s = b - 1;
        int js = (s == 0) ? 6 : (s == 1) ? 8 : 10;
        size_t woff = (size_t)js * 64 * 64;
        h16* Wp = Wcf + (size_t)s * 4096;
        for (int idx = t; idx < 512; idx += 256) {
            int c = idx >> 8, tt = (idx >> 6) & 3, ln = idx & 63;
            int quad = ln >> 4, col = tt * 16 + (ln & 15);
#pragma unroll
            for (int j = 0; j < 8; j++) {
                int k = c * 32 + quad * 8 + j;
                Wp[idx * 8 + j] = (h16)ldin(Wc, woff + (size_t)k * 64 + col, isbf);
            }
        }
    } else if (b == 4) {                       // W2f: f16 [6][3][64][8], cols>=40 zero
        for (int idx = t; idx < 1152; idx += 256) {
            int c = idx / 192, rem = idx % 192;
            int tt = rem >> 6, ln = rem & 63;
            int quad = ln >> 4, col = tt * 16 + (ln & 15);
#pragma unroll
            for (int j = 0; j < 8; j++) {
                int k = c * 32 + quad * 8 + j;
                float w = (col < 40) ? ldin(W2, (size_t)k * 40 + col, isbf) : 0.0f;
                W2f[idx * 8 + j] = (h16)w;
            }
        }
    } else {                                   // vectors + flag
        if (t == 0) *flag = isbf;
        if (t < 64) {
            vecs[t]       = ldin(b1, t, isbf);
            vecs[64 + t]  = ldin(g1, t, isbf);
            vecs[128 + t] = ldin(be1, t, isbf);
            vecs[192 + t] = ldin(bc, (size_t)6 * 64 + t, isbf);
            vecs[256 + t] = ldin(bc, (size_t)8 * 64 + t, isbf);
            vecs[320 + t] = ldin(bc, (size_t)10 * 64 + t, isbf);
        }
        if (t < 40) vecs[384 + t] = ldin(b2, t, isbf);
        if (t < 192) {
            float2 gb; gb.x = ldin(g2, t, isbf); gb.y = ldin(be2, t, isbf);
            GBv[t] = gb;
        }
    }
}

// ---------- 1. per-(block,bucket) histogram over contiguous chunks ----------
__global__ void k_bcnt(const int* __restrict__ dst, int* __restrict__ bcnt,
                       int* __restrict__ cnts, int E, int chunk) {
    __shared__ int c[NBMAX];
    int t = threadIdx.x, blk = blockIdx.x;
    c[t] = 0;
    __syncthreads();
    int beg = blk * chunk;
    int end = beg + chunk; if (end > E) end = E;
    for (int i = beg + t; i < end; i += 256)
        atomicAdd(&c[dst[i] >> 9], 1);
    __syncthreads();
    cnts[blk * NBMAX + t] = c[t];
    if (c[t] > 0) atomicAdd(&bcnt[t], c[t]);
}

// ---------- 2. fused: bucket-total scan (bbase) + per-bucket scan over block
// counts (base). Each block redundantly scans the 256 bucket totals. ----------
__global__ void k_colscan(const int* __restrict__ bcnt, const int* __restrict__ cnts,
                          int* __restrict__ bbase, int* __restrict__ base, int NB) {
    __shared__ int bsc[256];
    __shared__ int sh[256];
    __shared__ int bbs;
    int b = blockIdx.x, t = threadIdx.x;
    int bv = bcnt[t];
    bsc[t] = bv;
    __syncthreads();
    for (int s = 1; s < 256; s <<= 1) {
        int u = 0;
        if (t >= s) u = bsc[t - s];
        __syncthreads();
        bsc[t] += u;
        __syncthreads();
    }
    if (t == b) { bbs = bsc[t] - bv; bbase[b] = bbs; }
    if (b == 0 && t == 255) bbase[NB] = bsc[255];    // = E
    __syncthreads();
    int bb = bbs;
    int v[NBLK / 256];
    int s = 0;
#pragma unroll
    for (int j = 0; j < NBLK / 256; j++) {
        v[j] = cnts[(size_t)(t * (NBLK / 256) + j) * NBMAX + b];
        s += v[j];
    }
    sh[t] = s;
    __syncthreads();
    for (int st = 1; st < 256; st <<= 1) {
        int u = 0;
        if (t >= st) u = sh[t - st];
        __syncthreads();
        sh[t] += u;
        __syncthreads();
    }
    int run = bb + (t == 0 ? 0 : sh[t - 1]);
#pragma unroll
    for (int j = 0; j < NBLK / 256; j++) {
        base[(size_t)(t * (NBLK / 256) + j) * NBMAX + b] = run;
        run += v[j];
    }
}

// ---------- 3. deterministic scatter: packed (dst&511)<<23 | src ----------
__global__ void k_bin(const int* __restrict__ src, const int* __restrict__ dst,
                      const int* __restrict__ base, unsigned* __restrict__ stg,
                      int E, int chunk) {
    __shared__ int loc[NBMAX];
    int t = threadIdx.x, blk = blockIdx.x;
    loc[t] = base[(size_t)blk * NBMAX + t];
    __syncthreads();
    int beg = blk * chunk;
    int end = beg + chunk; if (end > E) end = E;
    for (int i = beg + t; i < end; i += 256) {
        int s = src[i], d = dst[i];
        int b = d >> 9;
        unsigned pr = ((unsigned)(d & 511) << 23) | (unsigned)s;
        int p = atomicAdd(&loc[b], 1);
        stg[p] = pr;
    }
}

// ---------- 4. per-bucket counting sort by (dstlocal, src>>14) ----------
__global__ void k_build2(const unsigned* __restrict__ stg, const int* __restrict__ bbase,
                         int* __restrict__ offv, float* __restrict__ dis,
                         float* __restrict__ d2, float* __restrict__ idis,
                         int* __restrict__ csr, int N, int E, int NB) {
    __shared__ int cnt2[4096];   // [dstlocal][srcblock]
    __shared__ int sc2[4096];    // inclusive scan
    __shared__ int pos2[4096];
    __shared__ int part[256];
    int b = blockIdx.x, t = threadIdx.x;
    for (int i = t; i < 4096; i += 256) { cnt2[i] = 0; pos2[i] = 0; }
    __syncthreads();
    int beg = bbase[b], end = bbase[b + 1];
    for (int k = beg + t; k < end; k += 256) {
        unsigned pr = stg[k];
        int dl = (int)(pr >> 23);
        int src = (int)(pr & 0x7FFFFFu);
        atomicAdd(&cnt2[dl * 8 + (src >> 14)], 1);
    }
    __syncthreads();
    int base16 = t * 16;
    int run = 0;
#pragma unroll
    for (int j = 0; j < 16; j++) { run += cnt2[base16 + j]; sc2[base16 + j] = run; }
    part[t] = run;
    __syncthreads();
    for (int s = 1; s < 256; s <<= 1) {
        int u = 0;
        if (t >= s) u = part[t - s];
        __syncthreads();
        part[t] += u;
        __syncthreads();
    }
    int add = (t == 0) ? 0 : part[t - 1];
#pragma unroll
    for (int j = 0; j < 16; j++) sc2[base16 + j] += add;   // global inclusive
    __syncthreads();
    int nb9 = b << 9;
#pragma unroll
    for (int ii = 0; ii < 2; ii++) {
        int dl = t + ii * 256;
        int node = nb9 + dl;
        if (node < N) {
            int k0 = dl * 8;
            int startk = sc2[k0] - cnt2[k0];
            int deg = sc2[k0 + 7] - startk;
            offv[node] = beg + startk;
            float dp1 = (float)(deg + 1);
            dis[node] = rsqrtf(dp1);
            d2[node] = 1.0f / dp1;
            idis[node] = sqrtf(dp1);
        }
    }
    if (b == NB - 1 && t == 0) offv[N] = E;
    __syncthreads();
    for (int k = beg + t; k < end; k += 256) {
        unsigned pr = stg[k];
        int dl = (int)(pr >> 23);
        int src = (int)(pr & 0x7FFFFFu);
        int key = dl * 8 + (src >> 14);
        int p = beg + (sc2[key] - cnt2[key]) + atomicAdd(&pos2[key], 1);
        csr[p] = src;
    }
}

// ---------- 5. s0 = dis * LN(gelu(x @ W1 + b1)) ; MFMA bf16, 16 nodes/wave ----------
__global__ void k_in(const void* __restrict__ x, const short* __restrict__ W1f,
                     const float* __restrict__ vecs, const float* __restrict__ dis,
                     h16* __restrict__ h, const int* __restrict__ flag, int N) {
    __shared__ __align__(16) short Bf[4][4][64][8];   // 16 KB, frag-order W1
    int isbf = *flag;
    int tid = threadIdx.x;
    {
        int4* d = (int4*)&Bf[0][0][0][0];
        const int4* s4 = (const int4*)W1f;
        for (int i = tid; i < 1024; i += 256) d[i] = s4[i];
    }
    __syncthreads();
    int lane = tid & 63, quad = lane >> 4, m15 = lane & 15;
    float bcol[4], gcol[4], ecol[4];
#pragma unroll
    for (int t = 0; t < 4; t++) {
        int col = t * 16 + m15;
        bcol[t] = vecs[col];
        gcol[t] = vecs[64 + col];
        ecol[t] = vecs[128 + col];
    }
    int wave = blockIdx.x * 4 + (tid >> 6);
    int nwave = gridDim.x * 4;
    int ntile = (N + 15) >> 4;
    for (int tile = wave; tile < ntile; tile += nwave) {
        int m0 = tile << 4;
        int mrow = m0 + m15; if (mrow >= N) mrow = N - 1;
        f32x4 acc[4];
#pragma unroll
        for (int t = 0; t < 4; t++)
#pragma unroll
            for (int r = 0; r < 4; r++) acc[t][r] = 0.0f;
#pragma unroll
        for (int c = 0; c < 4; c++) {
            short8 a;
            if (isbf) {
                a = *(const short8*)((const unsigned short*)x + (size_t)mrow * 128 + c * 32 + quad * 8);
            } else {
                const float* xp = (const float*)x + (size_t)mrow * 128 + c * 32 + quad * 8;
#pragma unroll
                for (int j = 0; j < 8; j++) a[j] = (short)f2bf(xp[j]);
            }
#pragma unroll
            for (int t = 0; t < 4; t++) {
                short8 b = *(const short8*)(&Bf[c][t][lane][0]);
                acc[t] = __builtin_amdgcn_mfma_f32_16x16x32_bf16(a, b, acc[t], 0, 0, 0);
            }
        }
        float v[4][4];
        float s[4] = {0, 0, 0, 0}, q[4] = {0, 0, 0, 0};
#pragma unroll
        for (int t = 0; t < 4; t++)
#pragma unroll
            for (int r = 0; r < 4; r++) {
                float g = gelu_fast(acc[t][r] + bcol[t]);
                v[t][r] = g;
                s[r] += g; q[r] += g * g;
            }
#pragma unroll
        for (int o = 1; o < 16; o <<= 1)
#pragma unroll
            for (int r = 0; r < 4; r++) {
                s[r] += __shfl_xor(s[r], o, 64);
                q[r] += __shfl_xor(q[r], o, 64);
            }
#pragma unroll
        for (int r = 0; r < 4; r++) {
            int node = m0 + quad * 4 + r;
            if (node < N) {
                float mu = s[r] * (1.0f / 64.0f);
                float var = q[r] * (1.0f / 64.0f) - mu * mu;
                float rs = rsqrtf(var + LN_EPS);
                float dn = dis[node];
#pragma unroll
                for (int t = 0; t < 4; t++) {
                    float hv = (v[t][r] - mu) * rs * gcol[t] + ecol[t];
                    h[(size_t)node * 64 + t * 16 + m15] = (h16)(dn * hv);
                }
            }
        }
    }
}

// ---------- 6. propagate: shared per-node body ----------
__device__ __forceinline__ void prop_node(const h16* __restrict__ cur,
                                          h16* __restrict__ nxt,
                                          const int* __restrict__ offv,
                                          const int* __restrict__ csr,
                                          const float* __restrict__ d2,
                                          int node, int g, int q) {
    h16x8 acc = {0, 0, 0, 0, 0, 0, 0, 0};
    int e = offv[node], end = offv[node + 1];
#pragma unroll 4
    for (; e + 8 <= end; e += 8) {
        int s = csr[e + g];
        acc += *(const h16x8*)(cur + (size_t)s * 64 + q * 8);
    }
    int r = end - e;
    if (g < r) {
        int s = csr[e + g];
        acc += *(const h16x8*)(cur + (size_t)s * 64 + q * 8);
    }
#pragma unroll
    for (int o = 8; o < 64; o <<= 1) {
        h16x8 other;
        int* ap = (int*)&acc;
        int* op = (int*)&other;
#pragma unroll
        for (int i = 0; i < 4; i++) op[i] = __shfl_xor(ap[i], o, 64);
        acc += other;
    }
    if (g == 0) {
        float dd = d2[node];
        h16x8 sv = *(const h16x8*)(cur + (size_t)node * 64 + q * 8);
        h16x8 o8;
#pragma unroll
        for (int i = 0; i < 8; i++) o8[i] = (h16)(dd * ((float)acc[i] + (float)sv[i]));
        *(h16x8*)(nxt + (size_t)node * 64 + q * 8) = o8;
    }
}

// classic single-hop (fallback path)
__global__ void k_prop(const h16* __restrict__ cur, h16* __restrict__ nxt,
                       const int* __restrict__ offv, const int* __restrict__ csr,
                       const float* __restrict__ d2, int N) {
    int node = blockIdx.x * 4 + (threadIdx.x >> 6);
    if (node >= N) return;
    int lane = threadIdx.x & 63;
    prop_node(cur, nxt, offv, csr, d2, node, lane >> 3, lane & 7);
}

// cooperative multi-hop: persistent grid, grid.sync() between hops.
// nhops must be even (result lands back in c0).
__global__ __launch_bounds__(256, 8)
void k_propN(h16* __restrict__ c0, h16* __restrict__ c1,
             const int* __restrict__ offv, const int* __restrict__ csr,
             const float* __restrict__ d2, int N, int nhops) {
    cg::grid_group grid = cg::this_grid();
    int wv = threadIdx.x >> 6;
    int lane = threadIdx.x & 63;
    int g = lane >> 3, q = lane & 7;
    int ngrp = (N + 3) >> 2;
    h16* cur = c0;
    h16* nxt = c1;
    for (int h = 0; h < nhops; h++) {
        for (int grp = blockIdx.x; grp < ngrp; grp += gridDim.x) {
            int node = grp * 4 + wv;
            if (node < N) prop_node(cur, nxt, offv, csr, d2, node, g, q);
        }
        grid.sync();
        h16* t = cur; cur = nxt; nxt = t;
    }
}

// ---------- 7. per-power linear: MFMA f16 ----------
__global__ void k_pout(const h16* __restrict__ cur, const h16* __restrict__ Wcf,
                       const float* __restrict__ bcv, const float* __restrict__ idis,
                       h16* __restrict__ hcat, int seg, int N) {
    __shared__ __align__(16) h16 Bf[2][4][64][8];   // 8 KB
    int tid = threadIdx.x;
    {
        int4* d = (int4*)&Bf[0][0][0][0];
        const int4* s4 = (const int4*)Wcf;
        for (int i = tid; i < 512; i += 256) d[i] = s4[i];
    }
    __syncthreads();
    int lane = tid & 63, quad = lane >> 4, m15 = lane & 15;
    float bcol[4];
#pragma unroll
    for (int t = 0; t < 4; t++) bcol[t] = bcv[t * 16 + m15];
    int wave = blockIdx.x * 4 + (tid >> 6);
    int nwave = gridDim.x * 4;
    int ntile = (N + 15) >> 4;
    for (int tile = wave; tile < ntile; tile += nwave) {
        int m0 = tile << 4;
        int mrow = m0 + m15; if (mrow >= N) mrow = N - 1;
        f32x4 acc[4];
#pragma unroll
        for (int t = 0; t < 4; t++)
#pragma unroll
            for (int r = 0; r < 4; r++) acc[t][r] = 0.0f;
#pragma unroll
        for (int c = 0; c < 2; c++) {
            h16x8 a = *(const h16x8*)(cur + (size_t)mrow * 64 + c * 32 + quad * 8);
#pragma unroll
            for (int t = 0; t < 4; t++) {
                h16x8 b = *(const h16x8*)(&Bf[c][t][lane][0]);
                acc[t] = __builtin_amdgcn_mfma_f32_16x16x32_f16(a, b, acc[t], 0, 0, 0);
            }
        }
#pragma unroll
        for (int r = 0; r < 4; r++) {
            int node = m0 + quad * 4 + r;
            if (node < N) {
                float di = idis[node];
#pragma unroll
                for (int t = 0; t < 4; t++)
                    hcat[(size_t)node * 192 + seg * 64 + t * 16 + m15] =
                        (h16)(bcol[t] + di * acc[t][r]);
            }
        }
    }
}

// ---------- 8. out = LN(gelu(hcat)) @ W2 + b2 ; MFMA f16, LN fused ----------
__global__ void k_fin(const h16* __restrict__ hcat, const h16* __restrict__ W2f,
                      const float* __restrict__ b2v, const float2* __restrict__ GBv,
                      void* __restrict__ out, const int* __restrict__ flag, int N) {
    __shared__ __align__(16) h16 Bf[6][3][64][8];   // 18 KB
    __shared__ float2 GBs[192];
    __shared__ __align__(16) h16 Y[4][16][200];     // raw gelu, per-wave
    int isbf = *flag;
    int tid = threadIdx.x;
    {
        int4* d = (int4*)&Bf[0][0][0][0];
        const int4* s4 = (const int4*)W2f;
        for (int i = tid; i < 1152; i += 256) d[i] = s4[i];
    }
    for (int i = tid; i < 192; i += 256) GBs[i] = GBv[i];
    __syncthreads();
    int wv = tid >> 6;
    int lane = tid & 63, quad = lane >> 4, m15 = lane & 15;
    float b2c[3];
#pragma unroll
    for (int t = 0; t < 3; t++) {
        int col = t * 16 + m15;
        b2c[t] = (col < 40) ? b2v[col] : 0.0f;
    }
    int wave = blockIdx.x * 4 + wv;
    int nwave = gridDim.x * 4;
    int ntile = (N + 15) >> 4;
    for (int tile = wave; tile < ntile; tile += nwave) {
        int m0 = tile << 4;
        int mrow = m0 + m15; if (mrow >= N) mrow = N - 1;
        const h16* hp = hcat + (size_t)mrow * 192 + quad * 48;
        float s = 0.0f, q = 0.0f;
#pragma unroll
        for (int u = 0; u < 6; u++) {
            h16x8 vv = *(const h16x8*)(hp + u * 8);
            h16x8 gv;
#pragma unroll
            for (int j = 0; j < 8; j++) {
                float g = gelu_fast((float)vv[j]);
                gv[j] = (h16)g;
                s += g; q += g * g;
            }
            *(h16x8*)(&Y[wv][m15][quad * 48 + u * 8]) = gv;
        }
        s += __shfl_xor(s, 16, 64); s += __shfl_xor(s, 32, 64);
        q += __shfl_xor(q, 16, 64); q += __shfl_xor(q, 32, 64);
        float mu = s * (1.0f / 192.0f);
        float var = q * (1.0f / 192.0f) - mu * mu;
        float rs = rsqrtf(var + LN_EPS);
        asm volatile("s_waitcnt lgkmcnt(0)" ::: "memory");   // cross-lane LDS RAW
        f32x4 acc[3];
#pragma unroll
        for (int t = 0; t < 3; t++)
#pragma unroll
            for (int r = 0; r < 4; r++) acc[t][r] = 0.0f;
#pragma unroll
        for (int c = 0; c < 6; c++) {
            h16x8 raw = *(const h16x8*)(&Y[wv][m15][c * 32 + quad * 8]);
            h16x8 a;
#pragma unroll
            for (int j = 0; j < 8; j++) {
                int k = c * 32 + quad * 8 + j;
                float2 gb = GBs[k];
                a[j] = (h16)(((float)raw[j] - mu) * rs * gb.x + gb.y);
            }
#pragma unroll
            for (int t = 0; t < 3; t++) {
                h16x8 b = *(const h16x8*)(&Bf[c][t][lane][0]);
                acc[t] = __builtin_amdgcn_mfma_f32_16x16x32_f16(a, b, acc[t], 0, 0, 0);
            }
        }
        asm volatile("" ::: "memory");
#pragma unroll
        for (int r = 0; r < 4; r++) {
            int node = m0 + quad * 4 + r;
            if (node < N) {
#pragma unroll
                for (int t = 0; t < 3; t++) {
                    int col = t * 16 + m15;
                    if (col < 40) {
                        float o = acc[t][r] + b2c[t];
                        if (isbf) ((unsigned short*)out)[(size_t)node * 40 + col] = f2bf(o);
                        else      ((float*)out)[(size_t)node * 40 + col] = o;
                    }
                }
            }
        }
    }
}

extern "C" void kernel_launch(void* const* d_in, const int* in_sizes, int n_in,
                              void* d_out, int out_size, void* d_ws, size_t ws_size,
                              hipStream_t stream) {
    const int IN = 128, HID = 64;
    const int N = in_sizes[0] / IN;        // 100000
    const int E = in_sizes[1] / 2;         // 3200000
    const int NB = (N + 511) >> 9;         // 196 dst-buckets
    const int chunk = (E + NBLK - 1) / NBLK;

    const void* x   = d_in[0];
    const int*  ei  = (const int*)d_in[1];
    const void* W1  = d_in[2];
    const void* b1  = d_in[3];
    const void* Wc  = d_in[4];
    const void* bc  = d_in[5];
    const void* W2  = d_in[6];
    const void* b2  = d_in[7];
    const void* g1  = d_in[8];
    const void* be1 = d_in[9];
    const void* g2  = d_in[10];
    const void* be2 = d_in[11];

    char* ws = (char*)d_ws;
    size_t off = 0;
    auto take = [&](size_t bytes) -> char* {
        char* p = ws + off;
        off = (off + bytes + 255) & ~(size_t)255;
        return p;
    };
    int*   flag  = (int*)take(256);
    int*   bcnt  = (int*)take(NBMAX * 4);
    int*   bbase = (int*)take((NBMAX + 1) * 4);
    float* dis   = (float*)take((size_t)N * 4);
    float* d2    = (float*)take((size_t)N * 4);
    float* idis  = (float*)take((size_t)N * 4);
    int*   offv  = (int*)take((size_t)(N + 1) * 4);
    int*   csr   = (int*)take((size_t)E * 4);
    // stg (E*4B, dead after k_build2) overlays hcat (N*384B, written later)
    size_t unionSz = (size_t)E * 4 > (size_t)N * 384 ? (size_t)E * 4 : (size_t)N * 384;
    char*  uni   = take(unionSz);
    unsigned* stg = (unsigned*)uni;
    h16*   hcat  = (h16*)uni;
    h16*   hA    = (h16*)take((size_t)N * HID * 2);
    h16*   hB    = (h16*)take((size_t)N * HID * 2);
    short* W1f  = (short*)take(16384);
    h16*   Wcf  = (h16*)take(24576);
    h16*   W2f  = (h16*)take(18432);
    float* vecs = (float*)take(2048);
    float2* GBv = (float2*)take(1536);
    // cnts/base (1 MB each) overlay csr: consumed before k_build2 writes csr.
    int*   cnts  = csr;
    int*   base  = csr + (size_t)NBLK * NBMAX;

    hipMemsetAsync(bcnt, 0, NBMAX * 4, stream);

    const int* srcp = ei;
    const int* dstp = ei + E;
    int gNode = (N + 3) / 4;
    int gDense = 1563;

    k_prep<<<6, 256, 0, stream>>>(W1, b1, g1, be1, Wc, bc, W2, b2, g2, be2, flag,
                                  W1f, Wcf, W2f, vecs, GBv);
    k_bcnt<<<NBLK, 256, 0, stream>>>(dstp, bcnt, cnts, E, chunk);
    k_colscan<<<NB, 256, 0, stream>>>(bcnt, cnts, bbase, base, NB);
    k_bin<<<NBLK, 256, 0, stream>>>(srcp, dstp, base, stg, E, chunk);
    k_build2<<<NB, 256, 0, stream>>>(stg, bbase, offv, dis, d2, idis, csr, N, E, NB);

    k_in<<<gDense, 256, 0, stream>>>(x, W1f, vecs, dis, hA, flag, N);

    // cooperative multi-hop segments (fallback: classic per-hop launches)
    int mb = 0;
    bool coopOK =
        (hipOccupancyMaxActiveBlocksPerMultiprocessor(&mb, k_propN, 256, 0) == hipSuccess)
        && mb > 0;
    int coopGrid = mb * 256;   // 256 CUs on MI355X
    auto runSeg = [&](h16* a, h16* b, int nh) {
        if (coopOK) {
            h16* pa = a; h16* pb = b;
            const int* po = offv; const int* pc = csr; const float* pd = d2;
            int pn = N; int ph = nh;
            void* args[] = {&pa, &pb, &po, &pc, &pd, &pn, &ph};
            if (hipLaunchCooperativeKernel(k_propN, dim3(coopGrid), dim3(256),
                                           args, 0u, stream) == hipSuccess)
                return;
            coopOK = false;    // don't retry a failing path
        }
        h16* c = a; h16* xb = b;
        for (int j = 0; j < nh; j++) {
            k_prop<<<gNode, 256, 0, stream>>>(c, xb, offv, csr, d2, N);
            h16* t = c; c = xb; xb = t;
        }
    };

    // hops 1-6 (result in hA), pout; 7-8, pout; 9-10, pout.
    runSeg(hA, hB, 6);
    k_pout<<<gDense, 256, 0, stream>>>(hA, Wcf, vecs + 192, idis, hcat, 0, N);
    runSeg(hA, hB, 2);
    k_pout<<<gDense, 256, 0, stream>>>(hA, Wcf + 4096, vecs + 256, idis, hcat, 1, N);
    runSeg(hA, hB, 2);
    k_pout<<<gDense, 256, 0, stream>>>(hA, Wcf + 8192, vecs + 320, idis, hcat, 2, N);

    k_fin<<<gDense, 256, 0, stream>>>(hcat, W2f, vecs + 384, GBv, d_out, flag, N);
}

// Round 6
// 844.322 us; speedup vs baseline: 3.3839x; 3.3839x over previous
//
#include <hip/hip_runtime.h>

typedef _Float16 h16;
typedef _Float16 h16x8 __attribute__((ext_vector_type(8)));
typedef short short8 __attribute__((ext_vector_type(8)));
typedef float f32x4 __attribute__((ext_vector_type(4)));

// ---------- bf16 helpers (bit-level) ----------
__device__ __forceinline__ float bf2f(unsigned short u) {
    return __uint_as_float(((unsigned)u) << 16);
}
__device__ __forceinline__ unsigned short f2bf(float f) {
    unsigned x = __float_as_uint(f);
    unsigned r = x + 0x7fffu + ((x >> 16) & 1u);   // round-to-nearest-even
    return (unsigned short)(r >> 16);
}
__device__ __forceinline__ float gelu_fast(float v) {
    float y = 0.7978845608f * (v + 0.044715f * v * v * v);
    float e = __expf(2.0f * y);
    float th = 1.0f - 2.0f * __builtin_amdgcn_rcpf(e + 1.0f);
    return 0.5f * v * (1.0f + th);
}

// flag-aware input load: isbf=1 -> buffer holds bf16, else fp32. i = element idx.
__device__ __forceinline__ float ldin(const void* p, size_t i, int isbf) {
    return isbf ? bf2f(((const unsigned short*)p)[i]) : ((const float*)p)[i];
}

#define LN_EPS 1e-5f
#define NBMAX 256
#define NBLK 1024

// ---------- 0b. one-time weight transpose into MFMA frag layout ----------
// Derives dtype flag itself (writes it for k_in/k_fin).
// vecs layout (floats): [0:64) b1 | [64:128) g1 | [128:192) be1
//                       [192:384) bc for j=6,8,10 | [384:424) b2
__global__ void k_prep(const void* __restrict__ W1, const void* __restrict__ b1,
                       const void* __restrict__ g1, const void* __restrict__ be1,
                       const void* __restrict__ Wc, const void* __restrict__ bc,
                       const void* __restrict__ W2, const void* __restrict__ b2,
                       const void* __restrict__ g2, const void* __restrict__ be2,
                       int* __restrict__ flag,
                       short* __restrict__ W1f, h16* __restrict__ Wcf,
                       h16* __restrict__ W2f, float* __restrict__ vecs,
                       float2* __restrict__ GBv) {
    int isbf = (((const unsigned*)g1)[0] == 0x3F803F80u) ? 1 : 0;
    int t = threadIdx.x, b = blockIdx.x;
    if (b == 0) {                              // W1f: bf16 [4][4][64][8]
        for (int idx = t; idx < 1024; idx += 256) {
            int c = idx >> 8, tt = (idx >> 6) & 3, ln = idx & 63;
            int quad = ln >> 4, col = tt * 16 + (ln & 15);
#pragma unroll
            for (int j = 0; j < 8; j++) {
                int k = c * 32 + quad * 8 + j;
                W1f[idx * 8 + j] = (short)f2bf(ldin(W1, (size_t)k * 64 + col, isbf));
            }
        }
    } else if (b <= 3) {                       // Wcf[s]: f16 [2][4][64][8], s=0,1,2 -> j=6,8,10
        int s = b - 1;
        int js = (s == 0) ? 6 : (s == 1) ? 8 : 10;
        size_t woff = (size_t)js * 64 * 64;
        h16* Wp = Wcf + (size_t)s * 4096;
        for (int idx = t; idx < 512; idx += 256) {
            int c = idx >> 8, tt = (idx >> 6) & 3, ln = idx & 63;
            int quad = ln >> 4, col = tt * 16 + (ln & 15);
#pragma unroll
            for (int j = 0; j < 8; j++) {
                int k = c * 32 + quad * 8 + j;
                Wp[idx * 8 + j] = (h16)ldin(Wc, woff + (size_t)k * 64 + col, isbf);
            }
        }
    } else if (b == 4) {                       // W2f: f16 [6][3][64][8], cols>=40 zero
        for (int idx = t; idx < 1152; idx += 256) {
            int c = idx / 192, rem = idx % 192;
            int tt = rem >> 6, ln = rem & 63;
            int quad = ln >> 4, col = tt * 16 + (ln & 15);
#pragma unroll
            for (int j = 0; j < 8; j++) {
                int k = c * 32 + quad * 8 + j;
                float w = (col < 40) ? ldin(W2, (size_t)k * 40 + col, isbf) : 0.0f;
                W2f[idx * 8 + j] = (h16)w;
            }
        }
    } else {                                   // vectors + flag
        if (t == 0) *flag = isbf;
        if (t < 64) {
            vecs[t]       = ldin(b1, t, isbf);
            vecs[64 + t]  = ldin(g1, t, isbf);
            vecs[128 + t] = ldin(be1, t, isbf);
            vecs[192 + t] = ldin(bc, (size_t)6 * 64 + t, isbf);
            vecs[256 + t] = ldin(bc, (size_t)8 * 64 + t, isbf);
            vecs[320 + t] = ldin(bc, (size_t)10 * 64 + t, isbf);
        }
        if (t < 40) vecs[384 + t] = ldin(b2, t, isbf);
        if (t < 192) {
            float2 gb; gb.x = ldin(g2, t, isbf); gb.y = ldin(be2, t, isbf);
            GBv[t] = gb;
        }
    }
}

// ---------- 1. per-(block,bucket) histogram over contiguous chunks ----------
__global__ void k_bcnt(const int* __restrict__ dst, int* __restrict__ bcnt,
                       int* __restrict__ cnts, int E, int chunk) {
    __shared__ int c[NBMAX];
    int t = threadIdx.x, blk = blockIdx.x;
    c[t] = 0;
    __syncthreads();
    int beg = blk * chunk;
    int end = beg + chunk; if (end > E) end = E;
    for (int i = beg + t; i < end; i += 256)
        atomicAdd(&c[dst[i] >> 9], 1);
    __syncthreads();
    cnts[blk * NBMAX + t] = c[t];
    if (c[t] > 0) atomicAdd(&bcnt[t], c[t]);
}

// ---------- 2. fused: bucket-total scan (bbase) + per-bucket scan over block
// counts (base). Each block redundantly scans the 256 bucket totals. ----------
__global__ void k_colscan(const int* __restrict__ bcnt, const int* __restrict__ cnts,
                          int* __restrict__ bbase, int* __restrict__ base, int NB) {
    __shared__ int bsc[256];
    __shared__ int sh[256];
    __shared__ int bbs;
    int b = blockIdx.x, t = threadIdx.x;
    int bv = bcnt[t];
    bsc[t] = bv;
    __syncthreads();
    for (int s = 1; s < 256; s <<= 1) {
        int u = 0;
        if (t >= s) u = bsc[t - s];
        __syncthreads();
        bsc[t] += u;
        __syncthreads();
    }
    if (t == b) { bbs = bsc[t] - bv; bbase[b] = bbs; }
    if (b == 0 && t == 255) bbase[NB] = bsc[255];    // = E
    __syncthreads();
    int bb = bbs;
    int v[NBLK / 256];
    int s = 0;
#pragma unroll
    for (int j = 0; j < NBLK / 256; j++) {
        v[j] = cnts[(size_t)(t * (NBLK / 256) + j) * NBMAX + b];
        s += v[j];
    }
    sh[t] = s;
    __syncthreads();
    for (int st = 1; st < 256; st <<= 1) {
        int u = 0;
        if (t >= st) u = sh[t - st];
        __syncthreads();
        sh[t] += u;
        __syncthreads();
    }
    int run = bb + (t == 0 ? 0 : sh[t - 1]);
#pragma unroll
    for (int j = 0; j < NBLK / 256; j++) {
        base[(size_t)(t * (NBLK / 256) + j) * NBMAX + b] = run;
        run += v[j];
    }
}

// ---------- 3. deterministic scatter: packed (dst&511)<<23 | src ----------
__global__ void k_bin(const int* __restrict__ src, const int* __restrict__ dst,
                      const int* __restrict__ base, unsigned* __restrict__ stg,
                      int E, int chunk) {
    __shared__ int loc[NBMAX];
    int t = threadIdx.x, blk = blockIdx.x;
    loc[t] = base[(size_t)blk * NBMAX + t];
    __syncthreads();
    int beg = blk * chunk;
    int end = beg + chunk; if (end > E) end = E;
    for (int i = beg + t; i < end; i += 256) {
        int s = src[i], d = dst[i];
        int b = d >> 9;
        unsigned pr = ((unsigned)(d & 511) << 23) | (unsigned)s;
        int p = atomicAdd(&loc[b], 1);
        stg[p] = pr;
    }
}

// ---------- 4. per-bucket counting sort by (dstlocal, src>>14) ----------
__global__ void k_build2(const unsigned* __restrict__ stg, const int* __restrict__ bbase,
                         int* __restrict__ offv, float* __restrict__ dis,
                         float* __restrict__ d2, float* __restrict__ idis,
                         int* __restrict__ csr, int N, int E, int NB) {
    __shared__ int cnt2[4096];   // [dstlocal][srcblock]
    __shared__ int sc2[4096];    // inclusive scan
    __shared__ int pos2[4096];
    __shared__ int part[256];
    int b = blockIdx.x, t = threadIdx.x;
    for (int i = t; i < 4096; i += 256) { cnt2[i] = 0; pos2[i] = 0; }
    __syncthreads();
    int beg = bbase[b], end = bbase[b + 1];
    for (int k = beg + t; k < end; k += 256) {
        unsigned pr = stg[k];
        int dl = (int)(pr >> 23);
        int src = (int)(pr & 0x7FFFFFu);
        atomicAdd(&cnt2[dl * 8 + (src >> 14)], 1);
    }
    __syncthreads();
    int base16 = t * 16;
    int run = 0;
#pragma unroll
    for (int j = 0; j < 16; j++) { run += cnt2[base16 + j]; sc2[base16 + j] = run; }
    part[t] = run;
    __syncthreads();
    for (int s = 1; s < 256; s <<= 1) {
        int u = 0;
        if (t >= s) u = part[t - s];
        __syncthreads();
        part[t] += u;
        __syncthreads();
    }
    int add = (t == 0) ? 0 : part[t - 1];
#pragma unroll
    for (int j = 0; j < 16; j++) sc2[base16 + j] += add;   // global inclusive
    __syncthreads();
    int nb9 = b << 9;
#pragma unroll
    for (int ii = 0; ii < 2; ii++) {
        int dl = t + ii * 256;
        int node = nb9 + dl;
        if (node < N) {
            int k0 = dl * 8;
            int startk = sc2[k0] - cnt2[k0];
            int deg = sc2[k0 + 7] - startk;
            offv[node] = beg + startk;
            float dp1 = (float)(deg + 1);
            dis[node] = rsqrtf(dp1);
            d2[node] = 1.0f / dp1;
            idis[node] = sqrtf(dp1);
        }
    }
    if (b == NB - 1 && t == 0) offv[N] = E;
    __syncthreads();
    for (int k = beg + t; k < end; k += 256) {
        unsigned pr = stg[k];
        int dl = (int)(pr >> 23);
        int src = (int)(pr & 0x7FFFFFu);
        int key = dl * 8 + (src >> 14);
        int p = beg + (sc2[key] - cnt2[key]) + atomicAdd(&pos2[key], 1);
        csr[p] = src;
    }
}

// ---------- 5. s0 = dis * LN(gelu(x @ W1 + b1)) ; MFMA bf16, 16 nodes/wave ----------
__global__ void k_in(const void* __restrict__ x, const short* __restrict__ W1f,
                     const float* __restrict__ vecs, const float* __restrict__ dis,
                     h16* __restrict__ h, const int* __restrict__ flag, int N) {
    __shared__ __align__(16) short Bf[4][4][64][8];   // 16 KB, frag-order W1
    int isbf = *flag;
    int tid = threadIdx.x;
    {
        int4* d = (int4*)&Bf[0][0][0][0];
        const int4* s4 = (const int4*)W1f;
        for (int i = tid; i < 1024; i += 256) d[i] = s4[i];
    }
    __syncthreads();
    int lane = tid & 63, quad = lane >> 4, m15 = lane & 15;
    float bcol[4], gcol[4], ecol[4];
#pragma unroll
    for (int t = 0; t < 4; t++) {
        int col = t * 16 + m15;
        bcol[t] = vecs[col];
        gcol[t] = vecs[64 + col];
        ecol[t] = vecs[128 + col];
    }
    int wave = blockIdx.x * 4 + (tid >> 6);
    int nwave = gridDim.x * 4;
    int ntile = (N + 15) >> 4;
    for (int tile = wave; tile < ntile; tile += nwave) {
        int m0 = tile << 4;
        int mrow = m0 + m15; if (mrow >= N) mrow = N - 1;
        f32x4 acc[4];
#pragma unroll
        for (int t = 0; t < 4; t++)
#pragma unroll
            for (int r = 0; r < 4; r++) acc[t][r] = 0.0f;
#pragma unroll
        for (int c = 0; c < 4; c++) {
            short8 a;
            if (isbf) {
                a = *(const short8*)((const unsigned short*)x + (size_t)mrow * 128 + c * 32 + quad * 8);
            } else {
                const float* xp = (const float*)x + (size_t)mrow * 128 + c * 32 + quad * 8;
#pragma unroll
                for (int j = 0; j < 8; j++) a[j] = (short)f2bf(xp[j]);
            }
#pragma unroll
            for (int t = 0; t < 4; t++) {
                short8 b = *(const short8*)(&Bf[c][t][lane][0]);
                acc[t] = __builtin_amdgcn_mfma_f32_16x16x32_bf16(a, b, acc[t], 0, 0, 0);
            }
        }
        float v[4][4];
        float s[4] = {0, 0, 0, 0}, q[4] = {0, 0, 0, 0};
#pragma unroll
        for (int t = 0; t < 4; t++)
#pragma unroll
            for (int r = 0; r < 4; r++) {
                float g = gelu_fast(acc[t][r] + bcol[t]);
                v[t][r] = g;
                s[r] += g; q[r] += g * g;
            }
#pragma unroll
        for (int o = 1; o < 16; o <<= 1)
#pragma unroll
            for (int r = 0; r < 4; r++) {
                s[r] += __shfl_xor(s[r], o, 64);
                q[r] += __shfl_xor(q[r], o, 64);
            }
#pragma unroll
        for (int r = 0; r < 4; r++) {
            int node = m0 + quad * 4 + r;
            if (node < N) {
                float mu = s[r] * (1.0f / 64.0f);
                float var = q[r] * (1.0f / 64.0f) - mu * mu;
                float rs = rsqrtf(var + LN_EPS);
                float dn = dis[node];
#pragma unroll
                for (int t = 0; t < 4; t++) {
                    float hv = (v[t][r] - mu) * rs * gcol[t] + ecol[t];
                    h[(size_t)node * 64 + t * 16 + m15] = (h16)(dn * hv);
                }
            }
        }
    }
}

// ---------- 6. propagate scaled state; 16 edges in flight per wave ----------
// 16 groups x 4 lanes, 32 B/lane (two h16x8 halves): deg~32 resolves in one
// unrolled csr->gather round-trip (half the dependent-chain depth of 8x8).
__global__ void k_prop(const h16* __restrict__ cur, h16* __restrict__ nxt,
                       const int* __restrict__ offv, const int* __restrict__ csr,
                       const float* __restrict__ d2, int N) {
    int node = blockIdx.x * 4 + (threadIdx.x >> 6);
    if (node >= N) return;
    int lane = threadIdx.x & 63;
    int g = lane >> 2, q = lane & 3;
    h16x8 acc0 = {0, 0, 0, 0, 0, 0, 0, 0};
    h16x8 acc1 = {0, 0, 0, 0, 0, 0, 0, 0};
    int e = offv[node], end = offv[node + 1];
#pragma unroll 2
    for (; e + 16 <= end; e += 16) {
        int s = csr[e + g];
        const h16* rp = cur + (size_t)s * 64 + q * 16;
        acc0 += *(const h16x8*)(rp);
        acc1 += *(const h16x8*)(rp + 8);
    }
    int r = end - e;
    if (g < r) {
        int s = csr[e + g];
        const h16* rp = cur + (size_t)s * 64 + q * 16;
        acc0 += *(const h16x8*)(rp);
        acc1 += *(const h16x8*)(rp + 8);
    }
#pragma unroll
    for (int o = 4; o < 64; o <<= 1) {
        h16x8 o0, o1;
        int* a0 = (int*)&acc0; int* p0 = (int*)&o0;
        int* a1 = (int*)&acc1; int* p1 = (int*)&o1;
#pragma unroll
        for (int i = 0; i < 4; i++) {
            p0[i] = __shfl_xor(a0[i], o, 64);
            p1[i] = __shfl_xor(a1[i], o, 64);
        }
        acc0 += o0; acc1 += o1;
    }
    if (g == 0) {
        float dd = d2[node];
        const h16* sp = cur + (size_t)node * 64 + q * 16;
        h16x8 sv0 = *(const h16x8*)(sp);
        h16x8 sv1 = *(const h16x8*)(sp + 8);
        h16x8 o80, o81;
#pragma unroll
        for (int i = 0; i < 8; i++) {
            o80[i] = (h16)(dd * ((float)acc0[i] + (float)sv0[i]));
            o81[i] = (h16)(dd * ((float)acc1[i] + (float)sv1[i]));
        }
        h16* np = nxt + (size_t)node * 64 + q * 16;
        *(h16x8*)(np) = o80;
        *(h16x8*)(np + 8) = o81;
    }
}

// ---------- 7. per-power linear: MFMA f16 ----------
__global__ void k_pout(const h16* __restrict__ cur, const h16* __restrict__ Wcf,
                       const float* __restrict__ bcv, const float* __restrict__ idis,
                       h16* __restrict__ hcat, int seg, int N) {
    __shared__ __align__(16) h16 Bf[2][4][64][8];   // 8 KB
    int tid = threadIdx.x;
    {
        int4* d = (int4*)&Bf[0][0][0][0];
        const int4* s4 = (const int4*)Wcf;
        for (int i = tid; i < 512; i += 256) d[i] = s4[i];
    }
    __syncthreads();
    int lane = tid & 63, quad = lane >> 4, m15 = lane & 15;
    float bcol[4];
#pragma unroll
    for (int t = 0; t < 4; t++) bcol[t] = bcv[t * 16 + m15];
    int wave = blockIdx.x * 4 + (tid >> 6);
    int nwave = gridDim.x * 4;
    int ntile = (N + 15) >> 4;
    for (int tile = wave; tile < ntile; tile += nwave) {
        int m0 = tile << 4;
        int mrow = m0 + m15; if (mrow >= N) mrow = N - 1;
        f32x4 acc[4];
#pragma unroll
        for (int t = 0; t < 4; t++)
#pragma unroll
            for (int r = 0; r < 4; r++) acc[t][r] = 0.0f;
#pragma unroll
        for (int c = 0; c < 2; c++) {
            h16x8 a = *(const h16x8*)(cur + (size_t)mrow * 64 + c * 32 + quad * 8);
#pragma unroll
            for (int t = 0; t < 4; t++) {
                h16x8 b = *(const h16x8*)(&Bf[c][t][lane][0]);
                acc[t] = __builtin_amdgcn_mfma_f32_16x16x32_f16(a, b, acc[t], 0, 0, 0);
            }
        }
#pragma unroll
        for (int r = 0; r < 4; r++) {
            int node = m0 + quad * 4 + r;
            if (node < N) {
                float di = idis[node];
#pragma unroll
                for (int t = 0; t < 4; t++)
                    hcat[(size_t)node * 192 + seg * 64 + t * 16 + m15] =
                        (h16)(bcol[t] + di * acc[t][r]);
            }
        }
    }
}

// ---------- 8. out = LN(gelu(hcat)) @ W2 + b2 ; MFMA f16, LN fused ----------
__global__ void k_fin(const h16* __restrict__ hcat, const h16* __restrict__ W2f,
                      const float* __restrict__ b2v, const float2* __restrict__ GBv,
                      void* __restrict__ out, const int* __restrict__ flag, int N) {
    __shared__ __align__(16) h16 Bf[6][3][64][8];   // 18 KB
    __shared__ float2 GBs[192];
    __shared__ __align__(16) h16 Y[4][16][200];     // raw gelu, per-wave
    int isbf = *flag;
    int tid = threadIdx.x;
    {
        int4* d = (int4*)&Bf[0][0][0][0];
        const int4* s4 = (const int4*)W2f;
        for (int i = tid; i < 1152; i += 256) d[i] = s4[i];
    }
    for (int i = tid; i < 192; i += 256) GBs[i] = GBv[i];
    __syncthreads();
    int wv = tid >> 6;
    int lane = tid & 63, quad = lane >> 4, m15 = lane & 15;
    float b2c[3];
#pragma unroll
    for (int t = 0; t < 3; t++) {
        int col = t * 16 + m15;
        b2c[t] = (col < 40) ? b2v[col] : 0.0f;
    }
    int wave = blockIdx.x * 4 + wv;
    int nwave = gridDim.x * 4;
    int ntile = (N + 15) >> 4;
    for (int tile = wave; tile < ntile; tile += nwave) {
        int m0 = tile << 4;
        int mrow = m0 + m15; if (mrow >= N) mrow = N - 1;
        const h16* hp = hcat + (size_t)mrow * 192 + quad * 48;
        float s = 0.0f, q = 0.0f;
#pragma unroll
        for (int u = 0; u < 6; u++) {
            h16x8 vv = *(const h16x8*)(hp + u * 8);
            h16x8 gv;
#pragma unroll
            for (int j = 0; j < 8; j++) {
                float g = gelu_fast((float)vv[j]);
                gv[j] = (h16)g;
                s += g; q += g * g;
            }
            *(h16x8*)(&Y[wv][m15][quad * 48 + u * 8]) = gv;
        }
        s += __shfl_xor(s, 16, 64); s += __shfl_xor(s, 32, 64);
        q += __shfl_xor(q, 16, 64); q += __shfl_xor(q, 32, 64);
        float mu = s * (1.0f / 192.0f);
        float var = q * (1.0f / 192.0f) - mu * mu;
        float rs = rsqrtf(var + LN_EPS);
        asm volatile("s_waitcnt lgkmcnt(0)" ::: "memory");   // cross-lane LDS RAW
        f32x4 acc[3];
#pragma unroll
        for (int t = 0; t < 3; t++)
#pragma unroll
            for (int r = 0; r < 4; r++) acc[t][r] = 0.0f;
#pragma unroll
        for (int c = 0; c < 6; c++) {
            h16x8 raw = *(const h16x8*)(&Y[wv][m15][c * 32 + quad * 8]);
            h16x8 a;
#pragma unroll
            for (int j = 0; j < 8; j++) {
                int k = c * 32 + quad * 8 + j;
                float2 gb = GBs[k];
                a[j] = (h16)(((float)raw[j] - mu) * rs * gb.x + gb.y);
            }
#pragma unroll
            for (int t = 0; t < 3; t++) {
                h16x8 b = *(const h16x8*)(&Bf[c][t][lane][0]);
                acc[t] = __builtin_amdgcn_mfma_f32_16x16x32_f16(a, b, acc[t], 0, 0, 0);
            }
        }
        asm volatile("" ::: "memory");
#pragma unroll
        for (int r = 0; r < 4; r++) {
            int node = m0 + quad * 4 + r;
            if (node < N) {
#pragma unroll
                for (int t = 0; t < 3; t++) {
                    int col = t * 16 + m15;
                    if (col < 40) {
                        float o = acc[t][r] + b2c[t];
                        if (isbf) ((unsigned short*)out)[(size_t)node * 40 + col] = f2bf(o);
                        else      ((float*)out)[(size_t)node * 40 + col] = o;
                    }
                }
            }
        }
    }
}

extern "C" void kernel_launch(void* const* d_in, const int* in_sizes, int n_in,
                              void* d_out, int out_size, void* d_ws, size_t ws_size,
                              hipStream_t stream) {
    const int IN = 128, HID = 64;
    const int N = in_sizes[0] / IN;        // 100000
    const int E = in_sizes[1] / 2;         // 3200000
    const int NB = (N + 511) >> 9;         // 196 dst-buckets
    const int chunk = (E + NBLK - 1) / NBLK;

    const void* x   = d_in[0];
    const int*  ei  = (const int*)d_in[1];
    const void* W1  = d_in[2];
    const void* b1  = d_in[3];
    const void* Wc  = d_in[4];
    const void* bc  = d_in[5];
    const void* W2  = d_in[6];
    const void* b2  = d_in[7];
    const void* g1  = d_in[8];
    const void* be1 = d_in[9];
    const void* g2  = d_in[10];
    const void* be2 = d_in[11];

    char* ws = (char*)d_ws;
    size_t off = 0;
    auto take = [&](size_t bytes) -> char* {
        char* p = ws + off;
        off = (off + bytes + 255) & ~(size_t)255;
        return p;
    };
    int*   flag  = (int*)take(256);
    int*   bcnt  = (int*)take(NBMAX * 4);
    int*   bbase = (int*)take((NBMAX + 1) * 4);
    float* dis   = (float*)take((size_t)N * 4);
    float* d2    = (float*)take((size_t)N * 4);
    float* idis  = (float*)take((size_t)N * 4);
    int*   offv  = (int*)take((size_t)(N + 1) * 4);
    int*   csr   = (int*)take((size_t)E * 4);
    // stg (E*4B, dead after k_build2) overlays hcat (N*384B, written later)
    size_t unionSz = (size_t)E * 4 > (size_t)N * 384 ? (size_t)E * 4 : (size_t)N * 384;
    char*  uni   = take(unionSz);
    unsigned* stg = (unsigned*)uni;
    h16*   hcat  = (h16*)uni;
    h16*   hA    = (h16*)take((size_t)N * HID * 2);
    h16*   hB    = (h16*)take((size_t)N * HID * 2);
    short* W1f  = (short*)take(16384);
    h16*   Wcf  = (h16*)take(24576);
    h16*   W2f  = (h16*)take(18432);
    float* vecs = (float*)take(2048);
    float2* GBv = (float2*)take(1536);
    // cnts/base (1 MB each) overlay csr: consumed before k_build2 writes csr.
    int*   cnts  = csr;
    int*   base  = csr + (size_t)NBLK * NBMAX;

    hipMemsetAsync(bcnt, 0, NBMAX * 4, stream);

    const int* srcp = ei;
    const int* dstp = ei + E;
    int gNode = (N + 3) / 4;
    int gDense = 1563;

    k_prep<<<6, 256, 0, stream>>>(W1, b1, g1, be1, Wc, bc, W2, b2, g2, be2, flag,
                                  W1f, Wcf, W2f, vecs, GBv);
    k_bcnt<<<NBLK, 256, 0, stream>>>(dstp, bcnt, cnts, E, chunk);
    k_colscan<<<NB, 256, 0, stream>>>(bcnt, cnts, bbase, base, NB);
    k_bin<<<NBLK, 256, 0, stream>>>(srcp, dstp, base, stg, E, chunk);
    k_build2<<<NB, 256, 0, stream>>>(stg, bbase, offv, dis, d2, idis, csr, N, E, NB);

    k_in<<<gDense, 256, 0, stream>>>(x, W1f, vecs, dis, hA, flag, N);
    h16* cur = hA; h16* nxt = hB;
    int seg = 0;
    for (int j = 1; j <= 10; j++) {
        k_prop<<<gNode, 256, 0, stream>>>(cur, nxt, offv, csr, d2, N);
        h16* tmp = cur; cur = nxt; nxt = tmp;
        if (j == 6 || j == 8 || j == 10) {
            k_pout<<<gDense, 256, 0, stream>>>(cur, Wcf + (size_t)seg * 4096,
                                               vecs + 192 + seg * 64, idis,
                                               hcat, seg, N);
            seg++;
        }
    }
    k_fin<<<gDense, 256, 0, stream>>>(hcat, W2f, vecs + 384, GBv, d_out, flag, N);
}

// Round 8
// 826.922 us; speedup vs baseline: 3.4551x; 1.0210x over previous
//
#include <hip/hip_runtime.h>

typedef _Float16 h16;
typedef _Float16 h16x8 __attribute__((ext_vector_type(8)));
typedef short short8 __attribute__((ext_vector_type(8)));
typedef float f32x4 __attribute__((ext_vector_type(4)));

// ---------- bf16 helpers (bit-level) ----------
__device__ __forceinline__ float bf2f(unsigned short u) {
    return __uint_as_float(((unsigned)u) << 16);
}
__device__ __forceinline__ unsigned short f2bf(float f) {
    unsigned x = __float_as_uint(f);
    unsigned r = x + 0x7fffu + ((x >> 16) & 1u);   // round-to-nearest-even
    return (unsigned short)(r >> 16);
}
__device__ __forceinline__ float gelu_fast(float v) {
    float y = 0.7978845608f * (v + 0.044715f * v * v * v);
    float e = __expf(2.0f * y);
    float th = 1.0f - 2.0f * __builtin_amdgcn_rcpf(e + 1.0f);
    return 0.5f * v * (1.0f + th);
}

// flag-aware input load: isbf=1 -> buffer holds bf16, else fp32. i = element idx.
__device__ __forceinline__ float ldin(const void* p, size_t i, int isbf) {
    return isbf ? bf2f(((const unsigned short*)p)[i]) : ((const float*)p)[i];
}

#define LN_EPS 1e-5f
#define NBMAX 256
#define NBLK 1024

// ---------- 0b. one-time weight transpose into MFMA frag layout ----------
// Derives dtype flag itself (writes it for k_in/k_fin).
// vecs layout (floats): [0:64) b1 | [64:128) g1 | [128:192) be1
//                       [192:384) bc for j=6,8,10 | [384:424) b2
__global__ void k_prep(const void* __restrict__ W1, const void* __restrict__ b1,
                       const void* __restrict__ g1, const void* __restrict__ be1,
                       const void* __restrict__ Wc, const void* __restrict__ bc,
                       const void* __restrict__ W2, const void* __restrict__ b2,
                       const void* __restrict__ g2, const void* __restrict__ be2,
                       int* __restrict__ flag,
                       short* __restrict__ W1f, h16* __restrict__ Wcf,
                       h16* __restrict__ W2f, float* __restrict__ vecs,
                       float2* __restrict__ GBv) {
    int isbf = (((const unsigned*)g1)[0] == 0x3F803F80u) ? 1 : 0;
    int t = threadIdx.x, b = blockIdx.x;
    if (b == 0) {                              // W1f: bf16 [4][4][64][8]
        for (int idx = t; idx < 1024; idx += 256) {
            int c = idx >> 8, tt = (idx >> 6) & 3, ln = idx & 63;
            int quad = ln >> 4, col = tt * 16 + (ln & 15);
#pragma unroll
            for (int j = 0; j < 8; j++) {
                int k = c * 32 + quad * 8 + j;
                W1f[idx * 8 + j] = (short)f2bf(ldin(W1, (size_t)k * 64 + col, isbf));
            }
        }
    } else if (b <= 3) {                       // Wcf[s]: f16 [2][4][64][8], s=0,1,2 -> j=6,8,10
        int s = b - 1;
        int js = (s == 0) ? 6 : (s == 1) ? 8 : 10;
        size_t woff = (size_t)js * 64 * 64;
        h16* Wp = Wcf + (size_t)s * 4096;
        for (int idx = t; idx < 512; idx += 256) {
            int c = idx >> 8, tt = (idx >> 6) & 3, ln = idx & 63;
            int quad = ln >> 4, col = tt * 16 + (ln & 15);
#pragma unroll
            for (int j = 0; j < 8; j++) {
                int k = c * 32 + quad * 8 + j;
                Wp[idx * 8 + j] = (h16)ldin(Wc, woff + (size_t)k * 64 + col, isbf);
            }
        }
    } else if (b == 4) {                       // W2f: f16 [6][3][64][8], cols>=40 zero
        for (int idx = t; idx < 1152; idx += 256) {
            int c = idx / 192, rem = idx % 192;
            int tt = rem >> 6, ln = rem & 63;
            int quad = ln >> 4, col = tt * 16 + (ln & 15);
#pragma unroll
            for (int j = 0; j < 8; j++) {
                int k = c * 32 + quad * 8 + j;
                float w = (col < 40) ? ldin(W2, (size_t)k * 40 + col, isbf) : 0.0f;
                W2f[idx * 8 + j] = (h16)w;
            }
        }
    } else {                                   // vectors + flag
        if (t == 0) *flag = isbf;
        if (t < 64) {
            vecs[t]       = ldin(b1, t, isbf);
            vecs[64 + t]  = ldin(g1, t, isbf);
            vecs[128 + t] = ldin(be1, t, isbf);
            vecs[192 + t] = ldin(bc, (size_t)6 * 64 + t, isbf);
            vecs[256 + t] = ldin(bc, (size_t)8 * 64 + t, isbf);
            vecs[320 + t] = ldin(bc, (size_t)10 * 64 + t, isbf);
        }
        if (t < 40) vecs[384 + t] = ldin(b2, t, isbf);
        if (t < 192) {
            float2 gb; gb.x = ldin(g2, t, isbf); gb.y = ldin(be2, t, isbf);
            GBv[t] = gb;
        }
    }
}

// ---------- 1. per-(block,bucket) histogram; int4-vectorized edge reads ----------
// chunk is a multiple of 4 so per-block segments stay 16-B aligned.
__global__ void k_bcnt(const int* __restrict__ dst, int* __restrict__ bcnt,
                       int* __restrict__ cnts, int E, int chunk) {
    __shared__ int c[NBMAX];
    int t = threadIdx.x, blk = blockIdx.x;
    c[t] = 0;
    __syncthreads();
    int beg = blk * chunk;
    int end = beg + chunk; if (end > E) end = E;
    for (int i0 = beg + t * 4; i0 < end; i0 += 1024) {
        if (i0 + 4 <= end) {
            int4 d4 = *(const int4*)(dst + i0);
            atomicAdd(&c[d4.x >> 9], 1);
            atomicAdd(&c[d4.y >> 9], 1);
            atomicAdd(&c[d4.z >> 9], 1);
            atomicAdd(&c[d4.w >> 9], 1);
        } else {
            for (int i = i0; i < end; i++) atomicAdd(&c[dst[i] >> 9], 1);
        }
    }
    __syncthreads();
    cnts[blk * NBMAX + t] = c[t];
    if (c[t] > 0) atomicAdd(&bcnt[t], c[t]);
}

// ---------- 2. fused: bucket-total scan (bbase) + per-bucket scan over block
// counts (base). Each block redundantly scans the 256 bucket totals. ----------
__global__ void k_colscan(const int* __restrict__ bcnt, const int* __restrict__ cnts,
                          int* __restrict__ bbase, int* __restrict__ base, int NB) {
    __shared__ int bsc[256];
    __shared__ int sh[256];
    __shared__ int bbs;
    int b = blockIdx.x, t = threadIdx.x;
    int bv = bcnt[t];
    bsc[t] = bv;
    __syncthreads();
    for (int s = 1; s < 256; s <<= 1) {
        int u = 0;
        if (t >= s) u = bsc[t - s];
        __syncthreads();
        bsc[t] += u;
        __syncthreads();
    }
    if (t == b) { bbs = bsc[t] - bv; bbase[b] = bbs; }
    if (b == 0 && t == 255) bbase[NB] = bsc[255];    // = E
    __syncthreads();
    int bb = bbs;
    int v[NBLK / 256];
    int s = 0;
#pragma unroll
    for (int j = 0; j < NBLK / 256; j++) {
        v[j] = cnts[(size_t)(t * (NBLK / 256) + j) * NBMAX + b];
        s += v[j];
    }
    sh[t] = s;
    __syncthreads();
    for (int st = 1; st < 256; st <<= 1) {
        int u = 0;
        if (t >= st) u = sh[t - st];
        __syncthreads();
        sh[t] += u;
        __syncthreads();
    }
    int run = bb + (t == 0 ? 0 : sh[t - 1]);
#pragma unroll
    for (int j = 0; j < NBLK / 256; j++) {
        base[(size_t)(t * (NBLK / 256) + j) * NBMAX + b] = run;
        run += v[j];
    }
}

// ---------- 3. deterministic scatter, int4 reads: packed (dst&511)<<23 | src ----------
__global__ void k_bin(const int* __restrict__ src, const int* __restrict__ dst,
                      const int* __restrict__ base, unsigned* __restrict__ stg,
                      int E, int chunk) {
    __shared__ int loc[NBMAX];
    int t = threadIdx.x, blk = blockIdx.x;
    loc[t] = base[(size_t)blk * NBMAX + t];
    __syncthreads();
    int beg = blk * chunk;
    int end = beg + chunk; if (end > E) end = E;
    for (int i0 = beg + t * 4; i0 < end; i0 += 1024) {
        bool full = (i0 + 4 <= end);
        int4 s4, d4;
        if (full) {
            s4 = *(const int4*)(src + i0);
            d4 = *(const int4*)(dst + i0);
        }
#pragma unroll
        for (int r = 0; r < 4; r++) {
            int i = i0 + r;
            int s, d;
            if (full) {
                s = ((const int*)&s4)[r]; d = ((const int*)&d4)[r];
            } else {
                if (i >= end) continue;
                s = src[i]; d = dst[i];
            }
            int b = d >> 9;
            unsigned pr = ((unsigned)(d & 511) << 23) | (unsigned)s;
            int p = atomicAdd(&loc[b], 1);
            stg[p] = pr;
        }
    }
}

// ---------- 4. per-bucket counting sort by (dstlocal, src>>14) ----------
__global__ void k_build2(const unsigned* __restrict__ stg, const int* __restrict__ bbase,
                         int* __restrict__ offv, float* __restrict__ dis,
                         float* __restrict__ d2, float* __restrict__ idis,
                         int* __restrict__ csr, int N, int E, int NB) {
    __shared__ int cnt2[4096];   // [dstlocal][srcblock]
    __shared__ int sc2[4096];    // inclusive scan
    __shared__ int pos2[4096];
    __shared__ int part[256];
    int b = blockIdx.x, t = threadIdx.x;
    for (int i = t; i < 4096; i += 256) { cnt2[i] = 0; pos2[i] = 0; }
    __syncthreads();
    int beg = bbase[b], end = bbase[b + 1];
    for (int k = beg + t; k < end; k += 256) {
        unsigned pr = stg[k];
        int dl = (int)(pr >> 23);
        int src = (int)(pr & 0x7FFFFFu);
        atomicAdd(&cnt2[dl * 8 + (src >> 14)], 1);
    }
    __syncthreads();
    int base16 = t * 16;
    int run = 0;
#pragma unroll
    for (int j = 0; j < 16; j++) { run += cnt2[base16 + j]; sc2[base16 + j] = run; }
    part[t] = run;
    __syncthreads();
    for (int s = 1; s < 256; s <<= 1) {
        int u = 0;
        if (t >= s) u = part[t - s];
        __syncthreads();
        part[t] += u;
        __syncthreads();
    }
    int add = (t == 0) ? 0 : part[t - 1];
#pragma unroll
    for (int j = 0; j < 16; j++) sc2[base16 + j] += add;   // global inclusive
    __syncthreads();
    int nb9 = b << 9;
#pragma unroll
    for (int ii = 0; ii < 2; ii++) {
        int dl = t + ii * 256;
        int node = nb9 + dl;
        if (node < N) {
            int k0 = dl * 8;
            int startk = sc2[k0] - cnt2[k0];
            int deg = sc2[k0 + 7] - startk;
            offv[node] = beg + startk;
            float dp1 = (float)(deg + 1);
            dis[node] = rsqrtf(dp1);
            d2[node] = 1.0f / dp1;
            idis[node] = sqrtf(dp1);
        }
    }
    if (b == NB - 1 && t == 0) offv[N] = E;
    __syncthreads();
    for (int k = beg + t; k < end; k += 256) {
        unsigned pr = stg[k];
        int dl = (int)(pr >> 23);
        int src = (int)(pr & 0x7FFFFFu);
        int key = dl * 8 + (src >> 14);
        int p = beg + (sc2[key] - cnt2[key]) + atomicAdd(&pos2[key], 1);
        csr[p] = src;
    }
}

// ---------- 5. s0 = dis * LN(gelu(x @ W1 + b1)) ; MFMA bf16, 16 nodes/wave ----------
__global__ void k_in(const void* __restrict__ x, const short* __restrict__ W1f,
                     const float* __restrict__ vecs, const float* __restrict__ dis,
                     h16* __restrict__ h, const int* __restrict__ flag, int N) {
    __shared__ __align__(16) short Bf[4][4][64][8];   // 16 KB, frag-order W1
    int isbf = *flag;
    int tid = threadIdx.x;
    {
        int4* d = (int4*)&Bf[0][0][0][0];
        const int4* s4 = (const int4*)W1f;
        for (int i = tid; i < 1024; i += 256) d[i] = s4[i];
    }
    __syncthreads();
    int lane = tid & 63, quad = lane >> 4, m15 = lane & 15;
    float bcol[4], gcol[4], ecol[4];
#pragma unroll
    for (int t = 0; t < 4; t++) {
        int col = t * 16 + m15;
        bcol[t] = vecs[col];
        gcol[t] = vecs[64 + col];
        ecol[t] = vecs[128 + col];
    }
    int wave = blockIdx.x * 4 + (tid >> 6);
    int nwave = gridDim.x * 4;
    int ntile = (N + 15) >> 4;
    for (int tile = wave; tile < ntile; tile += nwave) {
        int m0 = tile << 4;
        int mrow = m0 + m15; if (mrow >= N) mrow = N - 1;
        f32x4 acc[4];
#pragma unroll
        for (int t = 0; t < 4; t++)
#pragma unroll
            for (int r = 0; r < 4; r++) acc[t][r] = 0.0f;
#pragma unroll
        for (int c = 0; c < 4; c++) {
            short8 a;
            if (isbf) {
                a = *(const short8*)((const unsigned short*)x + (size_t)mrow * 128 + c * 32 + quad * 8);
            } else {
                const float* xp = (const float*)x + (size_t)mrow * 128 + c * 32 + quad * 8;
#pragma unroll
                for (int j = 0; j < 8; j++) a[j] = (short)f2bf(xp[j]);
            }
#pragma unroll
            for (int t = 0; t < 4; t++) {
                short8 b = *(const short8*)(&Bf[c][t][lane][0]);
                acc[t] = __builtin_amdgcn_mfma_f32_16x16x32_bf16(a, b, acc[t], 0, 0, 0);
            }
        }
        float v[4][4];
        float s[4] = {0, 0, 0, 0}, q[4] = {0, 0, 0, 0};
#pragma unroll
        for (int t = 0; t < 4; t++)
#pragma unroll
            for (int r = 0; r < 4; r++) {
                float g = gelu_fast(acc[t][r] + bcol[t]);
                v[t][r] = g;
                s[r] += g; q[r] += g * g;
            }
#pragma unroll
        for (int o = 1; o < 16; o <<= 1)
#pragma unroll
            for (int r = 0; r < 4; r++) {
                s[r] += __shfl_xor(s[r], o, 64);
                q[r] += __shfl_xor(q[r], o, 64);
            }
#pragma unroll
        for (int r = 0; r < 4; r++) {
            int node = m0 + quad * 4 + r;
            if (node < N) {
                float mu = s[r] * (1.0f / 64.0f);
                float var = q[r] * (1.0f / 64.0f) - mu * mu;
                float rs = rsqrtf(var + LN_EPS);
                float dn = dis[node];
#pragma unroll
                for (int t = 0; t < 4; t++) {
                    float hv = (v[t][r] - mu) * rs * gcol[t] + ecol[t];
                    h[(size_t)node * 64 + t * 16 + m15] = (h16)(dn * hv);
                }
            }
        }
    }
}

// ---------- 6. propagate scaled state; 16 edges in flight per wave ----------
__global__ void k_prop(const h16* __restrict__ cur, h16* __restrict__ nxt,
                       const int* __restrict__ offv, const int* __restrict__ csr,
                       const float* __restrict__ d2, int N) {
    int node = blockIdx.x * 4 + (threadIdx.x >> 6);
    if (node >= N) return;
    int lane = threadIdx.x & 63;
    int g = lane >> 2, q = lane & 3;
    h16x8 acc0 = {0, 0, 0, 0, 0, 0, 0, 0};
    h16x8 acc1 = {0, 0, 0, 0, 0, 0, 0, 0};
    int e = offv[node], end = offv[node + 1];
#pragma unroll 2
    for (; e + 16 <= end; e += 16) {
        int s = csr[e + g];
        const h16* rp = cur + (size_t)s * 64 + q * 16;
        acc0 += *(const h16x8*)(rp);
        acc1 += *(const h16x8*)(rp + 8);
    }
    int r = end - e;
    if (g < r) {
        int s = csr[e + g];
        const h16* rp = cur + (size_t)s * 64 + q * 16;
        acc0 += *(const h16x8*)(rp);
        acc1 += *(const h16x8*)(rp + 8);
    }
#pragma unroll
    for (int o = 4; o < 64; o <<= 1) {
        h16x8 o0, o1;
        int* a0 = (int*)&acc0; int* p0 = (int*)&o0;
        int* a1 = (int*)&acc1; int* p1 = (int*)&o1;
#pragma unroll
        for (int i = 0; i < 4; i++) {
            p0[i] = __shfl_xor(a0[i], o, 64);
            p1[i] = __shfl_xor(a1[i], o, 64);
        }
        acc0 += o0; acc1 += o1;
    }
    if (g == 0) {
        float dd = d2[node];
        const h16* sp = cur + (size_t)node * 64 + q * 16;
        h16x8 sv0 = *(const h16x8*)(sp);
        h16x8 sv1 = *(const h16x8*)(sp + 8);
        h16x8 o80, o81;
#pragma unroll
        for (int i = 0; i < 8; i++) {
            o80[i] = (h16)(dd * ((float)acc0[i] + (float)sv0[i]));
            o81[i] = (h16)(dd * ((float)acc1[i] + (float)sv1[i]));
        }
        h16* np = nxt + (size_t)node * 64 + q * 16;
        *(h16x8*)(np) = o80;
        *(h16x8*)(np + 8) = o81;
    }
}

// ---------- 7. per-power linear: MFMA f16 ----------
__global__ void k_pout(const h16* __restrict__ cur, const h16* __restrict__ Wcf,
                       const float* __restrict__ bcv, const float* __restrict__ idis,
                       h16* __restrict__ hcat, int seg, int N) {
    __shared__ __align__(16) h16 Bf[2][4][64][8];   // 8 KB
    int tid = threadIdx.x;
    {
        int4* d = (int4*)&Bf[0][0][0][0];
        const int4* s4 = (const int4*)Wcf;
        for (int i = tid; i < 512; i += 256) d[i] = s4[i];
    }
    __syncthreads();
    int lane = tid & 63, quad = lane >> 4, m15 = lane & 15;
    float bcol[4];
#pragma unroll
    for (int t = 0; t < 4; t++) bcol[t] = bcv[t * 16 + m15];
    int wave = blockIdx.x * 4 + (tid >> 6);
    int nwave = gridDim.x * 4;
    int ntile = (N + 15) >> 4;
    for (int tile = wave; tile < ntile; tile += nwave) {
        int m0 = tile << 4;
        int mrow = m0 + m15; if (mrow >= N) mrow = N - 1;
        f32x4 acc[4];
#pragma unroll
        for (int t = 0; t < 4; t++)
#pragma unroll
            for (int r = 0; r < 4; r++) acc[t][r] = 0.0f;
#pragma unroll
        for (int c = 0; c < 2; c++) {
            h16x8 a = *(const h16x8*)(cur + (size_t)mrow * 64 + c * 32 + quad * 8);
#pragma unroll
            for (int t = 0; t < 4; t++) {
                h16x8 b = *(const h16x8*)(&Bf[c][t][lane][0]);
                acc[t] = __builtin_amdgcn_mfma_f32_16x16x32_f16(a, b, acc[t], 0, 0, 0);
            }
        }
#pragma unroll
        for (int r = 0; r < 4; r++) {
            int node = m0 + quad * 4 + r;
            if (node < N) {
                float di = idis[node];
#pragma unroll
                for (int t = 0; t < 4; t++)
                    hcat[(size_t)node * 192 + seg * 64 + t * 16 + m15] =
                        (h16)(bcol[t] + di * acc[t][r]);
            }
        }
    }
}

// ---------- 8. out = LN(gelu(hcat)) @ W2 + b2 ; MFMA f16, LN fused ----------
__global__ void k_fin(const h16* __restrict__ hcat, const h16* __restrict__ W2f,
                      const float* __restrict__ b2v, const float2* __restrict__ GBv,
                      void* __restrict__ out, const int* __restrict__ flag, int N) {
    __shared__ __align__(16) h16 Bf[6][3][64][8];   // 18 KB
    __shared__ float2 GBs[192];
    __shared__ __align__(16) h16 Y[4][16][200];     // raw gelu, per-wave
    int isbf = *flag;
    int tid = threadIdx.x;
    {
        int4* d = (int4*)&Bf[0][0][0][0];
        const int4* s4 = (const int4*)W2f;
        for (int i = tid; i < 1152; i += 256) d[i] = s4[i];
    }
    for (int i = tid; i < 192; i += 256) GBs[i] = GBv[i];
    __syncthreads();
    int wv = tid >> 6;
    int lane = tid & 63, quad = lane >> 4, m15 = lane & 15;
    float b2c[3];
#pragma unroll
    for (int t = 0; t < 3; t++) {
        int col = t * 16 + m15;
        b2c[t] = (col < 40) ? b2v[col] : 0.0f;
    }
    int wave = blockIdx.x * 4 + wv;
    int nwave = gridDim.x * 4;
    int ntile = (N + 15) >> 4;
    for (int tile = wave; tile < ntile; tile += nwave) {
        int m0 = tile << 4;
        int mrow = m0 + m15; if (mrow >= N) mrow = N - 1;
        const h16* hp = hcat + (size_t)mrow * 192 + quad * 48;
        float s = 0.0f, q = 0.0f;
#pragma unroll
        for (int u = 0; u < 6; u++) {
            h16x8 vv = *(const h16x8*)(hp + u * 8);
            h16x8 gv;
#pragma unroll
            for (int j = 0; j < 8; j++) {
                float g = gelu_fast((float)vv[j]);
                gv[j] = (h16)g;
                s += g; q += g * g;
            }
            *(h16x8*)(&Y[wv][m15][quad * 48 + u * 8]) = gv;
        }
        s += __shfl_xor(s, 16, 64); s += __shfl_xor(s, 32, 64);
        q += __shfl_xor(q, 16, 64); q += __shfl_xor(q, 32, 64);
        float mu = s * (1.0f / 192.0f);
        float var = q * (1.0f / 192.0f) - mu * mu;
        float rs = rsqrtf(var + LN_EPS);
        asm volatile("s_waitcnt lgkmcnt(0)" ::: "memory");   // cross-lane LDS RAW
        f32x4 acc[3];
#pragma unroll
        for (int t = 0; t < 3; t++)
#pragma unroll
            for (int r = 0; r < 4; r++) acc[t][r] = 0.0f;
#pragma unroll
        for (int c = 0; c < 6; c++) {
            h16x8 raw = *(const h16x8*)(&Y[wv][m15][c * 32 + quad * 8]);
            h16x8 a;
#pragma unroll
            for (int j = 0; j < 8; j++) {
                int k = c * 32 + quad * 8 + j;
                float2 gb = GBs[k];
                a[j] = (h16)(((float)raw[j] - mu) * rs * gb.x + gb.y);
            }
#pragma unroll
            for (int t = 0; t < 3; t++) {
                h16x8 b = *(const h16x8*)(&Bf[c][t][lane][0]);
                acc[t] = __builtin_amdgcn_mfma_f32_16x16x32_f16(a, b, acc[t], 0, 0, 0);
            }
        }
        asm volatile("" ::: "memory");
#pragma unroll
        for (int r = 0; r < 4; r++) {
            int node = m0 + quad * 4 + r;
            if (node < N) {
#pragma unroll
                for (int t = 0; t < 3; t++) {
                    int col = t * 16 + m15;
                    if (col < 40) {
                        float o = acc[t][r] + b2c[t];
                        if (isbf) ((unsigned short*)out)[(size_t)node * 40 + col] = f2bf(o);
                        else      ((float*)out)[(size_t)node * 40 + col] = o;
                    }
                }
            }
        }
    }
}

extern "C" void kernel_launch(void* const* d_in, const int* in_sizes, int n_in,
                              void* d_out, int out_size, void* d_ws, size_t ws_size,
                              hipStream_t stream) {
    const int IN = 128, HID = 64;
    const int N = in_sizes[0] / IN;        // 100000
    const int E = in_sizes[1] / 2;         // 3200000
    const int NB = (N + 511) >> 9;         // 196 dst-buckets
    const int chunk = (((E + NBLK - 1) / NBLK) + 3) & ~3;   // 4-aligned for int4 reads

    const void* x   = d_in[0];
    const int*  ei  = (const int*)d_in[1];
    const void* W1  = d_in[2];
    const void* b1  = d_in[3];
    const void* Wc  = d_in[4];
    const void* bc  = d_in[5];
    const void* W2  = d_in[6];
    const void* b2  = d_in[7];
    const void* g1  = d_in[8];
    const void* be1 = d_in[9];
    const void* g2  = d_in[10];
    const void* be2 = d_in[11];

    char* ws = (char*)d_ws;
    size_t off = 0;
    auto take = [&](size_t bytes) -> char* {
        char* p = ws + off;
        off = (off + bytes + 255) & ~(size_t)255;
        return p;
    };
    int*   flag  = (int*)take(256);
    int*   bcnt  = (int*)take(NBMAX * 4);
    int*   bbase = (int*)take((NBMAX + 1) * 4);
    float* dis   = (float*)take((size_t)N * 4);
    float* d2    = (float*)take((size_t)N * 4);
    float* idis  = (float*)take((size_t)N * 4);
    int*   offv  = (int*)take((size_t)(N + 1) * 4);
    int*   csr   = (int*)take((size_t)E * 4);
    // stg (E*4B, dead after k_build2) overlays hcat (N*384B, written later)
    size_t unionSz = (size_t)E * 4 > (size_t)N * 384 ? (size_t)E * 4 : (size_t)N * 384;
    char*  uni   = take(unionSz);
    unsigned* stg = (unsigned*)uni;
    h16*   hcat  = (h16*)uni;
    h16*   hA    = (h16*)take((size_t)N * HID * 2);
    h16*   hB    = (h16*)take((size_t)N * HID * 2);
    short* W1f  = (short*)take(16384);
    h16*   Wcf  = (h16*)take(24576);
    h16*   W2f  = (h16*)take(18432);
    float* vecs = (float*)take(2048);
    float2* GBv = (float2*)take(1536);
    // cnts/base (1 MB each) overlay csr: consumed before k_build2 writes csr.
    int*   cnts  = csr;
    int*   base  = csr + (size_t)NBLK * NBMAX;

    hipMemsetAsync(bcnt, 0, NBMAX * 4, stream);

    const int* srcp = ei;
    const int* dstp = ei + E;
    int gNode = (N + 3) / 4;
    int gDense = 1563;

    k_prep<<<6, 256, 0, stream>>>(W1, b1, g1, be1, Wc, bc, W2, b2, g2, be2, flag,
                                  W1f, Wcf, W2f, vecs, GBv);
    k_bcnt<<<NBLK, 256, 0, stream>>>(dstp, bcnt, cnts, E, chunk);
    k_colscan<<<NB, 256, 0, stream>>>(bcnt, cnts, bbase, base, NB);
    k_bin<<<NBLK, 256, 0, stream>>>(srcp, dstp, base, stg, E, chunk);
    k_build2<<<NB, 256, 0, stream>>>(stg, bbase, offv, dis, d2, idis, csr, N, E, NB);

    k_in<<<gDense, 256, 0, stream>>>(x, W1f, vecs, dis, hA, flag, N);
    h16* cur = hA; h16* nxt = hB;
    int seg = 0;
    for (int j = 1; j <= 10; j++) {
        k_prop<<<gNode, 256, 0, stream>>>(cur, nxt, offv, csr, d2, N);
        h16* tmp = cur; cur = nxt; nxt = tmp;
        if (j == 6 || j == 8 || j == 10) {
            k_pout<<<gDense, 256, 0, stream>>>(cur, Wcf + (size_t)seg * 4096,
                                               vecs + 192 + seg * 64, idis,
                                               hcat, seg, N);
            seg++;
        }
    }
    k_fin<<<gDense, 256, 0, stream>>>(hcat, W2f, vecs + 384, GBv, d_out, flag, N);
}

// Round 9
// 822.335 us; speedup vs baseline: 3.4743x; 1.0056x over previous
//
#include <hip/hip_runtime.h>

typedef _Float16 h16;
typedef _Float16 h16x8 __attribute__((ext_vector_type(8)));
typedef short short8 __attribute__((ext_vector_type(8)));
typedef float f32x4 __attribute__((ext_vector_type(4)));

// ---------- bf16 helpers (bit-level) ----------
__device__ __forceinline__ float bf2f(unsigned short u) {
    return __uint_as_float(((unsigned)u) << 16);
}
__device__ __forceinline__ unsigned short f2bf(float f) {
    unsigned x = __float_as_uint(f);
    unsigned r = x + 0x7fffu + ((x >> 16) & 1u);   // round-to-nearest-even
    return (unsigned short)(r >> 16);
}
__device__ __forceinline__ float gelu_fast(float v) {
    float y = 0.7978845608f * (v + 0.044715f * v * v * v);
    float e = __expf(2.0f * y);
    float th = 1.0f - 2.0f * __builtin_amdgcn_rcpf(e + 1.0f);
    return 0.5f * v * (1.0f + th);
}

// flag-aware input load: isbf=1 -> buffer holds bf16, else fp32. i = element idx.
__device__ __forceinline__ float ldin(const void* p, size_t i, int isbf) {
    return isbf ? bf2f(((const unsigned short*)p)[i]) : ((const float*)p)[i];
}

#define LN_EPS 1e-5f
#define NBMAX 256
#define NBLK 1024
#define CHCAP 3328

// ---------- 0b. one-time weight transpose into MFMA frag layout ----------
// Derives dtype flag itself (writes it for k_in/k_fin).
// vecs layout (floats): [0:64) b1 | [64:128) g1 | [128:192) be1
//                       [192:384) bc for j=6,8,10 | [384:424) b2
__global__ void k_prep(const void* __restrict__ W1, const void* __restrict__ b1,
                       const void* __restrict__ g1, const void* __restrict__ be1,
                       const void* __restrict__ Wc, const void* __restrict__ bc,
                       const void* __restrict__ W2, const void* __restrict__ b2,
                       const void* __restrict__ g2, const void* __restrict__ be2,
                       int* __restrict__ flag,
                       short* __restrict__ W1f, h16* __restrict__ Wcf,
                       h16* __restrict__ W2f, float* __restrict__ vecs,
                       float2* __restrict__ GBv) {
    int isbf = (((const unsigned*)g1)[0] == 0x3F803F80u) ? 1 : 0;
    int t = threadIdx.x, b = blockIdx.x;
    if (b == 0) {                              // W1f: bf16 [4][4][64][8]
        for (int idx = t; idx < 1024; idx += 256) {
            int c = idx >> 8, tt = (idx >> 6) & 3, ln = idx & 63;
            int quad = ln >> 4, col = tt * 16 + (ln & 15);
#pragma unroll
            for (int j = 0; j < 8; j++) {
                int k = c * 32 + quad * 8 + j;
                W1f[idx * 8 + j] = (short)f2bf(ldin(W1, (size_t)k * 64 + col, isbf));
            }
        }
    } else if (b <= 3) {                       // Wcf[s]: f16 [2][4][64][8], s=0,1,2 -> j=6,8,10
        int s = b - 1;
        int js = (s == 0) ? 6 : (s == 1) ? 8 : 10;
        size_t woff = (size_t)js * 64 * 64;
        h16* Wp = Wcf + (size_t)s * 4096;
        for (int idx = t; idx < 512; idx += 256) {
            int c = idx >> 8, tt = (idx >> 6) & 3, ln = idx & 63;
            int quad = ln >> 4, col = tt * 16 + (ln & 15);
#pragma unroll
            for (int j = 0; j < 8; j++) {
                int k = c * 32 + quad * 8 + j;
                Wp[idx * 8 + j] = (h16)ldin(Wc, woff + (size_t)k * 64 + col, isbf);
            }
        }
    } else if (b == 4) {                       // W2f: f16 [6][3][64][8], cols>=40 zero
        for (int idx = t; idx < 1152; idx += 256) {
            int c = idx / 192, rem = idx % 192;
            int tt = rem >> 6, ln = rem & 63;
            int quad = ln >> 4, col = tt * 16 + (ln & 15);
#pragma unroll
            for (int j = 0; j < 8; j++) {
                int k = c * 32 + quad * 8 + j;
                float w = (col < 40) ? ldin(W2, (size_t)k * 40 + col, isbf) : 0.0f;
                W2f[idx * 8 + j] = (h16)w;
            }
        }
    } else {                                   // vectors + flag
        if (t == 0) *flag = isbf;
        if (t < 64) {
            vecs[t]       = ldin(b1, t, isbf);
            vecs[64 + t]  = ldin(g1, t, isbf);
            vecs[128 + t] = ldin(be1, t, isbf);
            vecs[192 + t] = ldin(bc, (size_t)6 * 64 + t, isbf);
            vecs[256 + t] = ldin(bc, (size_t)8 * 64 + t, isbf);
            vecs[320 + t] = ldin(bc, (size_t)10 * 64 + t, isbf);
        }
        if (t < 40) vecs[384 + t] = ldin(b2, t, isbf);
        if (t < 192) {
            float2 gb; gb.x = ldin(g2, t, isbf); gb.y = ldin(be2, t, isbf);
            GBv[t] = gb;
        }
    }
}

// ---------- 1. per-(block,bucket) histogram; int4-vectorized edge reads ----------
// chunk is a multiple of 4 so per-block segments stay 16-B aligned.
__global__ void k_bcnt(const int* __restrict__ dst, int* __restrict__ bcnt,
                       int* __restrict__ cnts, int E, int chunk) {
    __shared__ int c[NBMAX];
    int t = threadIdx.x, blk = blockIdx.x;
    c[t] = 0;
    __syncthreads();
    int beg = blk * chunk;
    int end = beg + chunk; if (end > E) end = E;
    for (int i0 = beg + t * 4; i0 < end; i0 += 1024) {
        if (i0 + 4 <= end) {
            int4 d4 = *(const int4*)(dst + i0);
            atomicAdd(&c[d4.x >> 9], 1);
            atomicAdd(&c[d4.y >> 9], 1);
            atomicAdd(&c[d4.z >> 9], 1);
            atomicAdd(&c[d4.w >> 9], 1);
        } else {
            for (int i = i0; i < end; i++) atomicAdd(&c[dst[i] >> 9], 1);
        }
    }
    __syncthreads();
    cnts[blk * NBMAX + t] = c[t];
    if (c[t] > 0) atomicAdd(&bcnt[t], c[t]);
}

// ---------- 2. fused: bucket-total scan (bbase) + per-bucket scan over block
// counts (base). Each block redundantly scans the 256 bucket totals. ----------
__global__ void k_colscan(const int* __restrict__ bcnt, const int* __restrict__ cnts,
                          int* __restrict__ bbase, int* __restrict__ base, int NB) {
    __shared__ int bsc[256];
    __shared__ int sh[256];
    __shared__ int bbs;
    int b = blockIdx.x, t = threadIdx.x;
    int bv = bcnt[t];
    bsc[t] = bv;
    __syncthreads();
    for (int s = 1; s < 256; s <<= 1) {
        int u = 0;
        if (t >= s) u = bsc[t - s];
        __syncthreads();
        bsc[t] += u;
        __syncthreads();
    }
    if (t == b) { bbs = bsc[t] - bv; bbase[b] = bbs; }
    if (b == 0 && t == 255) bbase[NB] = bsc[255];    // = E
    __syncthreads();
    int bb = bbs;
    int v[NBLK / 256];
    int s = 0;
#pragma unroll
    for (int j = 0; j < NBLK / 256; j++) {
        v[j] = cnts[(size_t)(t * (NBLK / 256) + j) * NBMAX + b];
        s += v[j];
    }
    sh[t] = s;
    __syncthreads();
    for (int st = 1; st < 256; st <<= 1) {
        int u = 0;
        if (t >= st) u = sh[t - st];
        __syncthreads();
        sh[t] += u;
        __syncthreads();
    }
    int run = bb + (t == 0 ? 0 : sh[t - 1]);
#pragma unroll
    for (int j = 0; j < NBLK / 256; j++) {
        base[(size_t)(t * (NBLK / 256) + j) * NBMAX + b] = run;
        run += v[j];
    }
}

// ---------- 3a. scatter via in-LDS counting sort: coalesced bucket-run writes ----------
__global__ void k_bin_sort(const int* __restrict__ src, const int* __restrict__ dst,
                           const int* __restrict__ base, unsigned* __restrict__ stg,
                           int E, int chunk) {
    __shared__ unsigned srt[CHCAP];
    __shared__ unsigned char bbk[CHCAP];
    __shared__ int cnt[NBMAX], lst[NBMAX], lpos[NBMAX], gbase[NBMAX];
    __shared__ int sh[256];
    int t = threadIdx.x, blk = blockIdx.x;
    cnt[t] = 0; lpos[t] = 0;
    gbase[t] = base[(size_t)blk * NBMAX + t];
    __syncthreads();
    int beg = blk * chunk;
    int end = beg + chunk; if (end > E) end = E;
    int cend = end - beg;
    // pass 1: local histogram
    for (int i0 = beg + t * 4; i0 < end; i0 += 1024) {
        if (i0 + 4 <= end) {
            int4 d4 = *(const int4*)(dst + i0);
            atomicAdd(&cnt[d4.x >> 9], 1);
            atomicAdd(&cnt[d4.y >> 9], 1);
            atomicAdd(&cnt[d4.z >> 9], 1);
            atomicAdd(&cnt[d4.w >> 9], 1);
        } else {
            for (int i = i0; i < end; i++) atomicAdd(&cnt[dst[i] >> 9], 1);
        }
    }
    __syncthreads();
    // exclusive scan -> lst
    int v = cnt[t];
    sh[t] = v;
    __syncthreads();
    for (int s = 1; s < 256; s <<= 1) {
        int u = 0;
        if (t >= s) u = sh[t - s];
        __syncthreads();
        sh[t] += u;
        __syncthreads();
    }
    lst[t] = sh[t] - v;
    __syncthreads();
    // pass 2: place into bucket-sorted LDS array
    for (int i0 = beg + t * 4; i0 < end; i0 += 1024) {
        bool full = (i0 + 4 <= end);
        int4 s4, d4;
        if (full) {
            s4 = *(const int4*)(src + i0);
            d4 = *(const int4*)(dst + i0);
        }
#pragma unroll
        for (int r = 0; r < 4; r++) {
            int i = i0 + r;
            int s, d;
            if (full) {
                s = ((const int*)&s4)[r]; d = ((const int*)&d4)[r];
            } else {
                if (i >= end) continue;
                s = src[i]; d = dst[i];
            }
            int b = d >> 9;
            unsigned pr = ((unsigned)(d & 511) << 23) | (unsigned)s;
            int p = lst[b] + atomicAdd(&lpos[b], 1);
            srt[p] = pr;
            bbk[p] = (unsigned char)b;
        }
    }
    __syncthreads();
    // write out: consecutive positions -> consecutive addresses within a bucket run
    for (int i = t; i < cend; i += 256) {
        int b = bbk[i];
        stg[gbase[b] + (i - lst[b])] = srt[i];
    }
}

// ---------- 3b. fallback scatter (chunk > CHCAP): scattered atomics ----------
__global__ void k_bin(const int* __restrict__ src, const int* __restrict__ dst,
                      const int* __restrict__ base, unsigned* __restrict__ stg,
                      int E, int chunk) {
    __shared__ int loc[NBMAX];
    int t = threadIdx.x, blk = blockIdx.x;
    loc[t] = base[(size_t)blk * NBMAX + t];
    __syncthreads();
    int beg = blk * chunk;
    int end = beg + chunk; if (end > E) end = E;
    for (int i0 = beg + t * 4; i0 < end; i0 += 1024) {
        bool full = (i0 + 4 <= end);
        int4 s4, d4;
        if (full) {
            s4 = *(const int4*)(src + i0);
            d4 = *(const int4*)(dst + i0);
        }
#pragma unroll
        for (int r = 0; r < 4; r++) {
            int i = i0 + r;
            int s, d;
            if (full) {
                s = ((const int*)&s4)[r]; d = ((const int*)&d4)[r];
            } else {
                if (i >= end) continue;
                s = src[i]; d = dst[i];
            }
            int b = d >> 9;
            unsigned pr = ((unsigned)(d & 511) << 23) | (unsigned)s;
            int p = atomicAdd(&loc[b], 1);
            stg[p] = pr;
        }
    }
}

// ---------- 4. per-bucket counting sort by (dstlocal, src>>14); 512 threads ----------
__global__ void k_build2(const unsigned* __restrict__ stg, const int* __restrict__ bbase,
                         int* __restrict__ offv, float* __restrict__ dis,
                         float* __restrict__ d2, float* __restrict__ idis,
                         int* __restrict__ csr, int N, int E, int NB) {
    __shared__ int cnt2[4096];   // [dstlocal][srcblock]
    __shared__ int sc2[4096];    // inclusive scan
    __shared__ int pos2[4096];
    __shared__ int part[512];
    int b = blockIdx.x, t = threadIdx.x;        // t < 512
    for (int i = t; i < 4096; i += 512) { cnt2[i] = 0; pos2[i] = 0; }
    __syncthreads();
    int beg = bbase[b], end = bbase[b + 1];
    for (int k = beg + t; k < end; k += 512) {
        unsigned pr = stg[k];
        int dl = (int)(pr >> 23);
        int src = (int)(pr & 0x7FFFFFu);
        atomicAdd(&cnt2[dl * 8 + (src >> 14)], 1);
    }
    __syncthreads();
    int base8 = t * 8;
    int run = 0;
#pragma unroll
    for (int j = 0; j < 8; j++) { run += cnt2[base8 + j]; sc2[base8 + j] = run; }
    part[t] = run;
    __syncthreads();
    for (int s = 1; s < 512; s <<= 1) {
        int u = 0;
        if (t >= s) u = part[t - s];
        __syncthreads();
        part[t] += u;
        __syncthreads();
    }
    int add = (t == 0) ? 0 : part[t - 1];
#pragma unroll
    for (int j = 0; j < 8; j++) sc2[base8 + j] += add;   // global inclusive
    __syncthreads();
    int nb9 = b << 9;
    {
        int dl = t;                                       // 512 dstlocal slots
        int node = nb9 + dl;
        if (node < N) {
            int k0 = dl * 8;
            int startk = sc2[k0] - cnt2[k0];
            int deg = sc2[k0 + 7] - startk;
            offv[node] = beg + startk;
            float dp1 = (float)(deg + 1);
            dis[node] = rsqrtf(dp1);
            d2[node] = 1.0f / dp1;
            idis[node] = sqrtf(dp1);
        }
    }
    if (b == NB - 1 && t == 0) offv[N] = E;
    __syncthreads();
    for (int k = beg + t; k < end; k += 512) {
        unsigned pr = stg[k];
        int dl = (int)(pr >> 23);
        int src = (int)(pr & 0x7FFFFFu);
        int key = dl * 8 + (src >> 14);
        int p = beg + (sc2[key] - cnt2[key]) + atomicAdd(&pos2[key], 1);
        csr[p] = src;
    }
}

// ---------- 5. s0 = dis * LN(gelu(x @ W1 + b1)) ; MFMA bf16, 16 nodes/wave ----------
__global__ void k_in(const void* __restrict__ x, const short* __restrict__ W1f,
                     const float* __restrict__ vecs, const float* __restrict__ dis,
                     h16* __restrict__ h, const int* __restrict__ flag, int N) {
    __shared__ __align__(16) short Bf[4][4][64][8];   // 16 KB, frag-order W1
    int isbf = *flag;
    int tid = threadIdx.x;
    {
        int4* d = (int4*)&Bf[0][0][0][0];
        const int4* s4 = (const int4*)W1f;
        for (int i = tid; i < 1024; i += 256) d[i] = s4[i];
    }
    __syncthreads();
    int lane = tid & 63, quad = lane >> 4, m15 = lane & 15;
    float bcol[4], gcol[4], ecol[4];
#pragma unroll
    for (int t = 0; t < 4; t++) {
        int col = t * 16 + m15;
        bcol[t] = vecs[col];
        gcol[t] = vecs[64 + col];
        ecol[t] = vecs[128 + col];
    }
    int wave = blockIdx.x * 4 + (tid >> 6);
    int nwave = gridDim.x * 4;
    int ntile = (N + 15) >> 4;
    for (int tile = wave; tile < ntile; tile += nwave) {
        int m0 = tile << 4;
        int mrow = m0 + m15; if (mrow >= N) mrow = N - 1;
        f32x4 acc[4];
#pragma unroll
        for (int t = 0; t < 4; t++)
#pragma unroll
            for (int r = 0; r < 4; r++) acc[t][r] = 0.0f;
#pragma unroll
        for (int c = 0; c < 4; c++) {
            short8 a;
            if (isbf) {
                a = *(const short8*)((const unsigned short*)x + (size_t)mrow * 128 + c * 32 + quad * 8);
            } else {
                const float* xp = (const float*)x + (size_t)mrow * 128 + c * 32 + quad * 8;
#pragma unroll
                for (int j = 0; j < 8; j++) a[j] = (short)f2bf(xp[j]);
            }
#pragma unroll
            for (int t = 0; t < 4; t++) {
                short8 b = *(const short8*)(&Bf[c][t][lane][0]);
                acc[t] = __builtin_amdgcn_mfma_f32_16x16x32_bf16(a, b, acc[t], 0, 0, 0);
            }
        }
        float v[4][4];
        float s[4] = {0, 0, 0, 0}, q[4] = {0, 0, 0, 0};
#pragma unroll
        for (int t = 0; t < 4; t++)
#pragma unroll
            for (int r = 0; r < 4; r++) {
                float g = gelu_fast(acc[t][r] + bcol[t]);
                v[t][r] = g;
                s[r] += g; q[r] += g * g;
            }
#pragma unroll
        for (int o = 1; o < 16; o <<= 1)
#pragma unroll
            for (int r = 0; r < 4; r++) {
                s[r] += __shfl_xor(s[r], o, 64);
                q[r] += __shfl_xor(q[r], o, 64);
            }
#pragma unroll
        for (int r = 0; r < 4; r++) {
            int node = m0 + quad * 4 + r;
            if (node < N) {
                float mu = s[r] * (1.0f / 64.0f);
                float var = q[r] * (1.0f / 64.0f) - mu * mu;
                float rs = rsqrtf(var + LN_EPS);
                float dn = dis[node];
#pragma unroll
                for (int t = 0; t < 4; t++) {
                    float hv = (v[t][r] - mu) * rs * gcol[t] + ecol[t];
                    h[(size_t)node * 64 + t * 16 + m15] = (h16)(dn * hv);
                }
            }
        }
    }
}

// ---------- 6. propagate scaled state; 16 edges in flight per wave; 8 nodes/block ----------
__global__ void k_prop(const h16* __restrict__ cur, h16* __restrict__ nxt,
                       const int* __restrict__ offv, const int* __restrict__ csr,
                       const float* __restrict__ d2, int N) {
    int node = blockIdx.x * 8 + (threadIdx.x >> 6);
    if (node >= N) return;
    int lane = threadIdx.x & 63;
    int g = lane >> 2, q = lane & 3;
    h16x8 acc0 = {0, 0, 0, 0, 0, 0, 0, 0};
    h16x8 acc1 = {0, 0, 0, 0, 0, 0, 0, 0};
    int e = offv[node], end = offv[node + 1];
#pragma unroll 2
    for (; e + 16 <= end; e += 16) {
        int s = csr[e + g];
        const h16* rp = cur + (size_t)s * 64 + q * 16;
        acc0 += *(const h16x8*)(rp);
        acc1 += *(const h16x8*)(rp + 8);
    }
    int r = end - e;
    if (g < r) {
        int s = csr[e + g];
        const h16* rp = cur + (size_t)s * 64 + q * 16;
        acc0 += *(const h16x8*)(rp);
        acc1 += *(const h16x8*)(rp + 8);
    }
#pragma unroll
    for (int o = 4; o < 64; o <<= 1) {
        h16x8 o0, o1;
        int* a0 = (int*)&acc0; int* p0 = (int*)&o0;
        int* a1 = (int*)&acc1; int* p1 = (int*)&o1;
#pragma unroll
        for (int i = 0; i < 4; i++) {
            p0[i] = __shfl_xor(a0[i], o, 64);
            p1[i] = __shfl_xor(a1[i], o, 64);
        }
        acc0 += o0; acc1 += o1;
    }
    if (g == 0) {
        float dd = d2[node];
        const h16* sp = cur + (size_t)node * 64 + q * 16;
        h16x8 sv0 = *(const h16x8*)(sp);
        h16x8 sv1 = *(const h16x8*)(sp + 8);
        h16x8 o80, o81;
#pragma unroll
        for (int i = 0; i < 8; i++) {
            o80[i] = (h16)(dd * ((float)acc0[i] + (float)sv0[i]));
            o81[i] = (h16)(dd * ((float)acc1[i] + (float)sv1[i]));
        }
        h16* np = nxt + (size_t)node * 64 + q * 16;
        *(h16x8*)(np) = o80;
        *(h16x8*)(np + 8) = o81;
    }
}

// ---------- 7. per-power linear: MFMA f16 ----------
__global__ void k_pout(const h16* __restrict__ cur, const h16* __restrict__ Wcf,
                       const float* __restrict__ bcv, const float* __restrict__ idis,
                       h16* __restrict__ hcat, int seg, int N) {
    __shared__ __align__(16) h16 Bf[2][4][64][8];   // 8 KB
    int tid = threadIdx.x;
    {
        int4* d = (int4*)&Bf[0][0][0][0];
        const int4* s4 = (const int4*)Wcf;
        for (int i = tid; i < 512; i += 256) d[i] = s4[i];
    }
    __syncthreads();
    int lane = tid & 63, quad = lane >> 4, m15 = lane & 15;
    float bcol[4];
#pragma unroll
    for (int t = 0; t < 4; t++) bcol[t] = bcv[t * 16 + m15];
    int wave = blockIdx.x * 4 + (tid >> 6);
    int nwave = gridDim.x * 4;
    int ntile = (N + 15) >> 4;
    for (int tile = wave; tile < ntile; tile += nwave) {
        int m0 = tile << 4;
        int mrow = m0 + m15; if (mrow >= N) mrow = N - 1;
        f32x4 acc[4];
#pragma unroll
        for (int t = 0; t < 4; t++)
#pragma unroll
            for (int r = 0; r < 4; r++) acc[t][r] = 0.0f;
#pragma unroll
        for (int c = 0; c < 2; c++) {
            h16x8 a = *(const h16x8*)(cur + (size_t)mrow * 64 + c * 32 + quad * 8);
#pragma unroll
            for (int t = 0; t < 4; t++) {
                h16x8 b = *(const h16x8*)(&Bf[c][t][lane][0]);
                acc[t] = __builtin_amdgcn_mfma_f32_16x16x32_f16(a, b, acc[t], 0, 0, 0);
            }
        }
#pragma unroll
        for (int r = 0; r < 4; r++) {
            int node = m0 + quad * 4 + r;
            if (node < N) {
                float di = idis[node];
#pragma unroll
                for (int t = 0; t < 4; t++)
                    hcat[(size_t)node * 192 + seg * 64 + t * 16 + m15] =
                        (h16)(bcol[t] + di * acc[t][r]);
            }
        }
    }
}

// ---------- 8. out = LN(gelu(hcat)) @ W2 + b2 ; MFMA f16, LN fused ----------
__global__ void k_fin(const h16* __restrict__ hcat, const h16* __restrict__ W2f,
                      const float* __restrict__ b2v, const float2* __restrict__ GBv,
                      void* __restrict__ out, const int* __restrict__ flag, int N) {
    __shared__ __align__(16) h16 Bf[6][3][64][8];   // 18 KB
    __shared__ float2 GBs[192];
    __shared__ __align__(16) h16 Y[4][16][200];     // raw gelu, per-wave
    int isbf = *flag;
    int tid = threadIdx.x;
    {
        int4* d = (int4*)&Bf[0][0][0][0];
        const int4* s4 = (const int4*)W2f;
        for (int i = tid; i < 1152; i += 256) d[i] = s4[i];
    }
    for (int i = tid; i < 192; i += 256) GBs[i] = GBv[i];
    __syncthreads();
    int wv = tid >> 6;
    int lane = tid & 63, quad = lane >> 4, m15 = lane & 15;
    float b2c[3];
#pragma unroll
    for (int t = 0; t < 3; t++) {
        int col = t * 16 + m15;
        b2c[t] = (col < 40) ? b2v[col] : 0.0f;
    }
    int wave = blockIdx.x * 4 + wv;
    int nwave = gridDim.x * 4;
    int ntile = (N + 15) >> 4;
    for (int tile = wave; tile < ntile; tile += nwave) {
        int m0 = tile << 4;
        int mrow = m0 + m15; if (mrow >= N) mrow = N - 1;
        const h16* hp = hcat + (size_t)mrow * 192 + quad * 48;
        float s = 0.0f, q = 0.0f;
#pragma unroll
        for (int u = 0; u < 6; u++) {
            h16x8 vv = *(const h16x8*)(hp + u * 8);
            h16x8 gv;
#pragma unroll
            for (int j = 0; j < 8; j++) {
                float g = gelu_fast((float)vv[j]);
                gv[j] = (h16)g;
                s += g; q += g * g;
            }
            *(h16x8*)(&Y[wv][m15][quad * 48 + u * 8]) = gv;
        }
        s += __shfl_xor(s, 16, 64); s += __shfl_xor(s, 32, 64);
        q += __shfl_xor(q, 16, 64); q += __shfl_xor(q, 32, 64);
        float mu = s * (1.0f / 192.0f);
        float var = q * (1.0f / 192.0f) - mu * mu;
        float rs = rsqrtf(var + LN_EPS);
        asm volatile("s_waitcnt lgkmcnt(0)" ::: "memory");   // cross-lane LDS RAW
        f32x4 acc[3];
#pragma unroll
        for (int t = 0; t < 3; t++)
#pragma unroll
            for (int r = 0; r < 4; r++) acc[t][r] = 0.0f;
#pragma unroll
        for (int c = 0; c < 6; c++) {
            h16x8 raw = *(const h16x8*)(&Y[wv][m15][c * 32 + quad * 8]);
            h16x8 a;
#pragma unroll
            for (int j = 0; j < 8; j++) {
                int k = c * 32 + quad * 8 + j;
                float2 gb = GBs[k];
                a[j] = (h16)(((float)raw[j] - mu) * rs * gb.x + gb.y);
            }
#pragma unroll
            for (int t = 0; t < 3; t++) {
                h16x8 b = *(const h16x8*)(&Bf[c][t][lane][0]);
                acc[t] = __builtin_amdgcn_mfma_f32_16x16x32_f16(a, b, acc[t], 0, 0, 0);
            }
        }
        asm volatile("" ::: "memory");
#pragma unroll
        for (int r = 0; r < 4; r++) {
            int node = m0 + quad * 4 + r;
            if (node < N) {
#pragma unroll
                for (int t = 0; t < 3; t++) {
                    int col = t * 16 + m15;
                    if (col < 40) {
                        float o = acc[t][r] + b2c[t];
                        if (isbf) ((unsigned short*)out)[(size_t)node * 40 + col] = f2bf(o);
                        else      ((float*)out)[(size_t)node * 40 + col] = o;
                    }
                }
            }
        }
    }
}

extern "C" void kernel_launch(void* const* d_in, const int* in_sizes, int n_in,
                              void* d_out, int out_size, void* d_ws, size_t ws_size,
                              hipStream_t stream) {
    const int IN = 128, HID = 64;
    const int N = in_sizes[0] / IN;        // 100000
    const int E = in_sizes[1] / 2;         // 3200000
    const int NB = (N + 511) >> 9;         // 196 dst-buckets
    const int chunk = (((E + NBLK - 1) / NBLK) + 3) & ~3;   // 4-aligned for int4 reads

    const void* x   = d_in[0];
    const int*  ei  = (const int*)d_in[1];
    const void* W1  = d_in[2];
    const void* b1  = d_in[3];
    const void* Wc  = d_in[4];
    const void* bc  = d_in[5];
    const void* W2  = d_in[6];
    const void* b2  = d_in[7];
    const void* g1  = d_in[8];
    const void* be1 = d_in[9];
    const void* g2  = d_in[10];
    const void* be2 = d_in[11];

    char* ws = (char*)d_ws;
    size_t off = 0;
    auto take = [&](size_t bytes) -> char* {
        char* p = ws + off;
        off = (off + bytes + 255) & ~(size_t)255;
        return p;
    };
    int*   flag  = (int*)take(256);
    int*   bcnt  = (int*)take(NBMAX * 4);
    int*   bbase = (int*)take((NBMAX + 1) * 4);
    float* dis   = (float*)take((size_t)N * 4);
    float* d2    = (float*)take((size_t)N * 4);
    float* idis  = (float*)take((size_t)N * 4);
    int*   offv  = (int*)take((size_t)(N + 1) * 4);
    int*   csr   = (int*)take((size_t)E * 4);
    // stg (E*4B, dead after k_build2) overlays hcat (N*384B, written later)
    size_t unionSz = (size_t)E * 4 > (size_t)N * 384 ? (size_t)E * 4 : (size_t)N * 384;
    char*  uni   = take(unionSz);
    unsigned* stg = (unsigned*)uni;
    h16*   hcat  = (h16*)uni;
    h16*   hA    = (h16*)take((size_t)N * HID * 2);
    h16*   hB    = (h16*)take((size_t)N * HID * 2);
    short* W1f  = (short*)take(16384);
    h16*   Wcf  = (h16*)take(24576);
    h16*   W2f  = (h16*)take(18432);
    float* vecs = (float*)take(2048);
    float2* GBv = (float2*)take(1536);
    // cnts/base (1 MB each) overlay csr: consumed before k_build2 writes csr.
    int*   cnts  = csr;
    int*   base  = csr + (size_t)NBLK * NBMAX;

    hipMemsetAsync(bcnt, 0, NBMAX * 4, stream);

    const int* srcp = ei;
    const int* dstp = ei + E;
    int gNode = (N + 7) / 8;
    int gDense = 1563;

    k_prep<<<6, 256, 0, stream>>>(W1, b1, g1, be1, Wc, bc, W2, b2, g2, be2, flag,
                                  W1f, Wcf, W2f, vecs, GBv);
    k_bcnt<<<NBLK, 256, 0, stream>>>(dstp, bcnt, cnts, E, chunk);
    k_colscan<<<NB, 256, 0, stream>>>(bcnt, cnts, bbase, base, NB);
    if (chunk <= CHCAP)
        k_bin_sort<<<NBLK, 256, 0, stream>>>(srcp, dstp, base, stg, E, chunk);
    else
        k_bin<<<NBLK, 256, 0, stream>>>(srcp, dstp, base, stg, E, chunk);
    k_build2<<<NB, 512, 0, stream>>>(stg, bbase, offv, dis, d2, idis, csr, N, E, NB);

    k_in<<<gDense, 256, 0, stream>>>(x, W1f, vecs, dis, hA, flag, N);
    h16* cur = hA; h16* nxt = hB;
    int seg = 0;
    for (int j = 1; j <= 10; j++) {
        k_prop<<<gNode, 512, 0, stream>>>(cur, nxt, offv, csr, d2, N);
        h16* tmp = cur; cur = nxt; nxt = tmp;
        if (j == 6 || j == 8 || j == 10) {
            k_pout<<<gDense, 256, 0, stream>>>(cur, Wcf + (size_t)seg * 4096,
                                               vecs + 192 + seg * 64, idis,
                                               hcat, seg, N);
            seg++;
        }
    }
    k_fin<<<gDense, 256, 0, stream>>>(hcat, W2f, vecs + 384, GBv, d_out, flag, N);
}

// Round 10
// 818.154 us; speedup vs baseline: 3.4921x; 1.0051x over previous
//
#include <hip/hip_runtime.h>

typedef _Float16 h16;
typedef _Float16 h16x8 __attribute__((ext_vector_type(8)));
typedef short short8 __attribute__((ext_vector_type(8)));
typedef float f32x4 __attribute__((ext_vector_type(4)));

// ---------- bf16 helpers (bit-level) ----------
__device__ __forceinline__ float bf2f(unsigned short u) {
    return __uint_as_float(((unsigned)u) << 16);
}
__device__ __forceinline__ unsigned short f2bf(float f) {
    unsigned x = __float_as_uint(f);
    unsigned r = x + 0x7fffu + ((x >> 16) & 1u);   // round-to-nearest-even
    return (unsigned short)(r >> 16);
}
__device__ __forceinline__ float gelu_fast(float v) {
    float y = 0.7978845608f * (v + 0.044715f * v * v * v);
    float e = __expf(2.0f * y);
    float th = 1.0f - 2.0f * __builtin_amdgcn_rcpf(e + 1.0f);
    return 0.5f * v * (1.0f + th);
}

// flag-aware input load: isbf=1 -> buffer holds bf16, else fp32. i = element idx.
__device__ __forceinline__ float ldin(const void* p, size_t i, int isbf) {
    return isbf ? bf2f(((const unsigned short*)p)[i]) : ((const float*)p)[i];
}

#define LN_EPS 1e-5f
#define NBMAX 256
#define NBLK 1024
#define CHCAP 3328

// ---------- 0b. one-time weight transpose into MFMA frag layout ----------
// Derives dtype flag itself; block 5 also zeroes bcnt (replaces memset dispatch).
// vecs layout (floats): [0:64) b1 | [64:128) g1 | [128:192) be1
//                       [192:384) bc for j=6,8,10 | [384:424) b2
__global__ void k_prep(const void* __restrict__ W1, const void* __restrict__ b1,
                       const void* __restrict__ g1, const void* __restrict__ be1,
                       const void* __restrict__ Wc, const void* __restrict__ bc,
                       const void* __restrict__ W2, const void* __restrict__ b2,
                       const void* __restrict__ g2, const void* __restrict__ be2,
                       int* __restrict__ flag, int* __restrict__ bcnt,
                       short* __restrict__ W1f, h16* __restrict__ Wcf,
                       h16* __restrict__ W2f, float* __restrict__ vecs,
                       float2* __restrict__ GBv) {
    int isbf = (((const unsigned*)g1)[0] == 0x3F803F80u) ? 1 : 0;
    int t = threadIdx.x, b = blockIdx.x;
    if (b == 0) {                              // W1f: bf16 [4][4][64][8]
        for (int idx = t; idx < 1024; idx += 256) {
            int c = idx >> 8, tt = (idx >> 6) & 3, ln = idx & 63;
            int quad = ln >> 4, col = tt * 16 + (ln & 15);
#pragma unroll
            for (int j = 0; j < 8; j++) {
                int k = c * 32 + quad * 8 + j;
                W1f[idx * 8 + j] = (short)f2bf(ldin(W1, (size_t)k * 64 + col, isbf));
            }
        }
    } else if (b <= 3) {                       // Wcf[s]: f16 [2][4][64][8], s=0,1,2 -> j=6,8,10
        int s = b - 1;
        int js = (s == 0) ? 6 : (s == 1) ? 8 : 10;
        size_t woff = (size_t)js * 64 * 64;
        h16* Wp = Wcf + (size_t)s * 4096;
        for (int idx = t; idx < 512; idx += 256) {
            int c = idx >> 8, tt = (idx >> 6) & 3, ln = idx & 63;
            int quad = ln >> 4, col = tt * 16 + (ln & 15);
#pragma unroll
            for (int j = 0; j < 8; j++) {
                int k = c * 32 + quad * 8 + j;
                Wp[idx * 8 + j] = (h16)ldin(Wc, woff + (size_t)k * 64 + col, isbf);
            }
        }
    } else if (b == 4) {                       // W2f: f16 [6][3][64][8], cols>=40 zero
        for (int idx = t; idx < 1152; idx += 256) {
            int c = idx / 192, rem = idx % 192;
            int tt = rem >> 6, ln = rem & 63;
            int quad = ln >> 4, col = tt * 16 + (ln & 15);
#pragma unroll
            for (int j = 0; j < 8; j++) {
                int k = c * 32 + quad * 8 + j;
                float w = (col < 40) ? ldin(W2, (size_t)k * 40 + col, isbf) : 0.0f;
                W2f[idx * 8 + j] = (h16)w;
            }
        }
    } else {                                   // vectors + flag + bcnt zero
        bcnt[t] = 0;
        if (t == 0) *flag = isbf;
        if (t < 64) {
            vecs[t]       = ldin(b1, t, isbf);
            vecs[64 + t]  = ldin(g1, t, isbf);
            vecs[128 + t] = ldin(be1, t, isbf);
            vecs[192 + t] = ldin(bc, (size_t)6 * 64 + t, isbf);
            vecs[256 + t] = ldin(bc, (size_t)8 * 64 + t, isbf);
            vecs[320 + t] = ldin(bc, (size_t)10 * 64 + t, isbf);
        }
        if (t < 40) vecs[384 + t] = ldin(b2, t, isbf);
        if (t < 192) {
            float2 gb; gb.x = ldin(g2, t, isbf); gb.y = ldin(be2, t, isbf);
            GBv[t] = gb;
        }
    }
}

// ---------- 1. per-(block,bucket) histogram; int4-vectorized edge reads ----------
// chunk is a multiple of 4 so per-block segments stay 16-B aligned.
__global__ void k_bcnt(const int* __restrict__ dst, int* __restrict__ bcnt,
                       int* __restrict__ cnts, int E, int chunk) {
    __shared__ int c[NBMAX];
    int t = threadIdx.x, blk = blockIdx.x;
    c[t] = 0;
    __syncthreads();
    int beg = blk * chunk;
    int end = beg + chunk; if (end > E) end = E;
    for (int i0 = beg + t * 4; i0 < end; i0 += 1024) {
        if (i0 + 4 <= end) {
            int4 d4 = *(const int4*)(dst + i0);
            atomicAdd(&c[d4.x >> 9], 1);
            atomicAdd(&c[d4.y >> 9], 1);
            atomicAdd(&c[d4.z >> 9], 1);
            atomicAdd(&c[d4.w >> 9], 1);
        } else {
            for (int i = i0; i < end; i++) atomicAdd(&c[dst[i] >> 9], 1);
        }
    }
    __syncthreads();
    cnts[blk * NBMAX + t] = c[t];
    if (c[t] > 0) atomicAdd(&bcnt[t], c[t]);
}

// ---------- 2. fused: bucket-total scan (bbase) + per-bucket scan over block
// counts (base). Each block redundantly scans the 256 bucket totals. ----------
__global__ void k_colscan(const int* __restrict__ bcnt, const int* __restrict__ cnts,
                          int* __restrict__ bbase, int* __restrict__ base, int NB) {
    __shared__ int bsc[256];
    __shared__ int sh[256];
    __shared__ int bbs;
    int b = blockIdx.x, t = threadIdx.x;
    int bv = bcnt[t];
    bsc[t] = bv;
    __syncthreads();
    for (int s = 1; s < 256; s <<= 1) {
        int u = 0;
        if (t >= s) u = bsc[t - s];
        __syncthreads();
        bsc[t] += u;
        __syncthreads();
    }
    if (t == b) { bbs = bsc[t] - bv; bbase[b] = bbs; }
    if (b == 0 && t == 255) bbase[NB] = bsc[255];    // = E
    __syncthreads();
    int bb = bbs;
    int v[NBLK / 256];
    int s = 0;
#pragma unroll
    for (int j = 0; j < NBLK / 256; j++) {
        v[j] = cnts[(size_t)(t * (NBLK / 256) + j) * NBMAX + b];
        s += v[j];
    }
    sh[t] = s;
    __syncthreads();
    for (int st = 1; st < 256; st <<= 1) {
        int u = 0;
        if (t >= st) u = sh[t - st];
        __syncthreads();
        sh[t] += u;
        __syncthreads();
    }
    int run = bb + (t == 0 ? 0 : sh[t - 1]);
#pragma unroll
    for (int j = 0; j < NBLK / 256; j++) {
        base[(size_t)(t * (NBLK / 256) + j) * NBMAX + b] = run;
        run += v[j];
    }
}

// ---------- 3a. scatter via in-LDS counting sort: coalesced bucket-run writes ----------
// Histogram row reloaded from cnts (computed by k_bcnt) instead of a second
// pass over dst — saves 25.6 MB of edge re-reads + 3.2M LDS atomics.
__global__ void k_bin_sort(const int* __restrict__ src, const int* __restrict__ dst,
                           const int* __restrict__ base, const int* __restrict__ cnts,
                           unsigned* __restrict__ stg, int E, int chunk) {
    __shared__ unsigned srt[CHCAP];
    __shared__ unsigned char bbk[CHCAP];
    __shared__ int lst[NBMAX], lpos[NBMAX], gbase[NBMAX];
    __shared__ int sh[256];
    int t = threadIdx.x, blk = blockIdx.x;
    lpos[t] = 0;
    gbase[t] = base[(size_t)blk * NBMAX + t];
    int v = cnts[(size_t)blk * NBMAX + t];
    sh[t] = v;
    __syncthreads();
    for (int s = 1; s < 256; s <<= 1) {
        int u = 0;
        if (t >= s) u = sh[t - s];
        __syncthreads();
        sh[t] += u;
        __syncthreads();
    }
    lst[t] = sh[t] - v;
    __syncthreads();
    int beg = blk * chunk;
    int end = beg + chunk; if (end > E) end = E;
    int cend = end - beg;
    // place into bucket-sorted LDS array
    for (int i0 = beg + t * 4; i0 < end; i0 += 1024) {
        bool full = (i0 + 4 <= end);
        int4 s4, d4;
        if (full) {
            s4 = *(const int4*)(src + i0);
            d4 = *(const int4*)(dst + i0);
        }
#pragma unroll
        for (int r = 0; r < 4; r++) {
            int i = i0 + r;
            int s, d;
            if (full) {
                s = ((const int*)&s4)[r]; d = ((const int*)&d4)[r];
            } else {
                if (i >= end) continue;
                s = src[i]; d = dst[i];
            }
            int b = d >> 9;
            unsigned pr = ((unsigned)(d & 511) << 23) | (unsigned)s;
            int p = lst[b] + atomicAdd(&lpos[b], 1);
            srt[p] = pr;
            bbk[p] = (unsigned char)b;
        }
    }
    __syncthreads();
    // write out: consecutive positions -> consecutive addresses within a bucket run
    for (int i = t; i < cend; i += 256) {
        int b = bbk[i];
        stg[gbase[b] + (i - lst[b])] = srt[i];
    }
}

// ---------- 3b. fallback scatter (chunk > CHCAP): scattered atomics ----------
__global__ void k_bin(const int* __restrict__ src, const int* __restrict__ dst,
                      const int* __restrict__ base, unsigned* __restrict__ stg,
                      int E, int chunk) {
    __shared__ int loc[NBMAX];
    int t = threadIdx.x, blk = blockIdx.x;
    loc[t] = base[(size_t)blk * NBMAX + t];
    __syncthreads();
    int beg = blk * chunk;
    int end = beg + chunk; if (end > E) end = E;
    for (int i0 = beg + t * 4; i0 < end; i0 += 1024) {
        bool full = (i0 + 4 <= end);
        int4 s4, d4;
        if (full) {
            s4 = *(const int4*)(src + i0);
            d4 = *(const int4*)(dst + i0);
        }
#pragma unroll
        for (int r = 0; r < 4; r++) {
            int i = i0 + r;
            int s, d;
            if (full) {
                s = ((const int*)&s4)[r]; d = ((const int*)&d4)[r];
            } else {
                if (i >= end) continue;
                s = src[i]; d = dst[i];
            }
            int b = d >> 9;
            unsigned pr = ((unsigned)(d & 511) << 23) | (unsigned)s;
            int p = atomicAdd(&loc[b], 1);
            stg[p] = pr;
        }
    }
}

// ---------- 4. per-bucket counting sort by (dstlocal, src>>14); 512 threads ----------
__global__ void k_build2(const unsigned* __restrict__ stg, const int* __restrict__ bbase,
                         int* __restrict__ offv, float* __restrict__ dis,
                         float* __restrict__ d2, float* __restrict__ idis,
                         int* __restrict__ csr, int N, int E, int NB) {
    __shared__ int cnt2[4096];   // [dstlocal][srcblock]
    __shared__ int sc2[4096];    // inclusive scan
    __shared__ int pos2[4096];
    __shared__ int part[512];
    int b = blockIdx.x, t = threadIdx.x;        // t < 512
    for (int i = t; i < 4096; i += 512) { cnt2[i] = 0; pos2[i] = 0; }
    __syncthreads();
    int beg = bbase[b], end = bbase[b + 1];
    for (int k = beg + t; k < end; k += 512) {
        unsigned pr = stg[k];
        int dl = (int)(pr >> 23);
        int src = (int)(pr & 0x7FFFFFu);
        atomicAdd(&cnt2[dl * 8 + (src >> 14)], 1);
    }
    __syncthreads();
    int base8 = t * 8;
    int run = 0;
#pragma unroll
    for (int j = 0; j < 8; j++) { run += cnt2[base8 + j]; sc2[base8 + j] = run; }
    part[t] = run;
    __syncthreads();
    for (int s = 1; s < 512; s <<= 1) {
        int u = 0;
        if (t >= s) u = part[t - s];
        __syncthreads();
        part[t] += u;
        __syncthreads();
    }
    int add = (t == 0) ? 0 : part[t - 1];
#pragma unroll
    for (int j = 0; j < 8; j++) sc2[base8 + j] += add;   // global inclusive
    __syncthreads();
    int nb9 = b << 9;
    {
        int dl = t;                                       // 512 dstlocal slots
        int node = nb9 + dl;
        if (node < N) {
            int k0 = dl * 8;
            int startk = sc2[k0] - cnt2[k0];
            int deg = sc2[k0 + 7] - startk;
            offv[node] = beg + startk;
            float dp1 = (float)(deg + 1);
            dis[node] = rsqrtf(dp1);
            d2[node] = 1.0f / dp1;
            idis[node] = sqrtf(dp1);
        }
    }
    if (b == NB - 1 && t == 0) offv[N] = E;
    __syncthreads();
    for (int k = beg + t; k < end; k += 512) {
        unsigned pr = stg[k];
        int dl = (int)(pr >> 23);
        int src = (int)(pr & 0x7FFFFFu);
        int key = dl * 8 + (src >> 14);
        int p = beg + (sc2[key] - cnt2[key]) + atomicAdd(&pos2[key], 1);
        csr[p] = src;
    }
}

// ---------- 5. s0 = dis * LN(gelu(x @ W1 + b1)) ; MFMA bf16, 16 nodes/wave ----------
__global__ void k_in(const void* __restrict__ x, const short* __restrict__ W1f,
                     const float* __restrict__ vecs, const float* __restrict__ dis,
                     h16* __restrict__ h, const int* __restrict__ flag, int N) {
    __shared__ __align__(16) short Bf[4][4][64][8];   // 16 KB, frag-order W1
    int isbf = *flag;
    int tid = threadIdx.x;
    {
        int4* d = (int4*)&Bf[0][0][0][0];
        const int4* s4 = (const int4*)W1f;
        for (int i = tid; i < 1024; i += 256) d[i] = s4[i];
    }
    __syncthreads();
    int lane = tid & 63, quad = lane >> 4, m15 = lane & 15;
    float bcol[4], gcol[4], ecol[4];
#pragma unroll
    for (int t = 0; t < 4; t++) {
        int col = t * 16 + m15;
        bcol[t] = vecs[col];
        gcol[t] = vecs[64 + col];
        ecol[t] = vecs[128 + col];
    }
    int wave = blockIdx.x * 4 + (tid >> 6);
    int nwave = gridDim.x * 4;
    int ntile = (N + 15) >> 4;
    for (int tile = wave; tile < ntile; tile += nwave) {
        int m0 = tile << 4;
        int mrow = m0 + m15; if (mrow >= N) mrow = N - 1;
        f32x4 acc[4];
#pragma unroll
        for (int t = 0; t < 4; t++)
#pragma unroll
            for (int r = 0; r < 4; r++) acc[t][r] = 0.0f;
#pragma unroll
        for (int c = 0; c < 4; c++) {
            short8 a;
            if (isbf) {
                a = *(const short8*)((const unsigned short*)x + (size_t)mrow * 128 + c * 32 + quad * 8);
            } else {
                const float* xp = (const float*)x + (size_t)mrow * 128 + c * 32 + quad * 8;
#pragma unroll
                for (int j = 0; j < 8; j++) a[j] = (short)f2bf(xp[j]);
            }
#pragma unroll
            for (int t = 0; t < 4; t++) {
                short8 b = *(const short8*)(&Bf[c][t][lane][0]);
                acc[t] = __builtin_amdgcn_mfma_f32_16x16x32_bf16(a, b, acc[t], 0, 0, 0);
            }
        }
        float v[4][4];
        float s[4] = {0, 0, 0, 0}, q[4] = {0, 0, 0, 0};
#pragma unroll
        for (int t = 0; t < 4; t++)
#pragma unroll
            for (int r = 0; r < 4; r++) {
                float g = gelu_fast(acc[t][r] + bcol[t]);
                v[t][r] = g;
                s[r] += g; q[r] += g * g;
            }
#pragma unroll
        for (int o = 1; o < 16; o <<= 1)
#pragma unroll
            for (int r = 0; r < 4; r++) {
                s[r] += __shfl_xor(s[r], o, 64);
                q[r] += __shfl_xor(q[r], o, 64);
            }
#pragma unroll
        for (int r = 0; r < 4; r++) {
            int node = m0 + quad * 4 + r;
            if (node < N) {
                float mu = s[r] * (1.0f / 64.0f);
                float var = q[r] * (1.0f / 64.0f) - mu * mu;
                float rs = rsqrtf(var + LN_EPS);
                float dn = dis[node];
#pragma unroll
                for (int t = 0; t < 4; t++) {
                    float hv = (v[t][r] - mu) * rs * gcol[t] + ecol[t];
                    h[(size_t)node * 64 + t * 16 + m15] = (h16)(dn * hv);
                }
            }
        }
    }
}

// ---------- 6. propagate scaled state; 16 edges in flight per wave; 8 nodes/block ----------
__global__ void k_prop(const h16* __restrict__ cur, h16* __restrict__ nxt,
                       const int* __restrict__ offv, const int* __restrict__ csr,
                       const float* __restrict__ d2, int N) {
    int node = blockIdx.x * 8 + (threadIdx.x >> 6);
    if (node >= N) return;
    int lane = threadIdx.x & 63;
    int g = lane >> 2, q = lane & 3;
    h16x8 acc0 = {0, 0, 0, 0, 0, 0, 0, 0};
    h16x8 acc1 = {0, 0, 0, 0, 0, 0, 0, 0};
    int e = offv[node], end = offv[node + 1];
#pragma unroll 2
    for (; e + 16 <= end; e += 16) {
        int s = csr[e + g];
        const h16* rp = cur + (size_t)s * 64 + q * 16;
        acc0 += *(const h16x8*)(rp);
        acc1 += *(const h16x8*)(rp + 8);
    }
    int r = end - e;
    if (g < r) {
        int s = csr[e + g];
        const h16* rp = cur + (size_t)s * 64 + q * 16;
        acc0 += *(const h16x8*)(rp);
        acc1 += *(const h16x8*)(rp + 8);
    }
#pragma unroll
    for (int o = 4; o < 64; o <<= 1) {
        h16x8 o0, o1;
        int* a0 = (int*)&acc0; int* p0 = (int*)&o0;
        int* a1 = (int*)&acc1; int* p1 = (int*)&o1;
#pragma unroll
        for (int i = 0; i < 4; i++) {
            p0[i] = __shfl_xor(a0[i], o, 64);
            p1[i] = __shfl_xor(a1[i], o, 64);
        }
        acc0 += o0; acc1 += o1;
    }
    if (g == 0) {
        float dd = d2[node];
        const h16* sp = cur + (size_t)node * 64 + q * 16;
        h16x8 sv0 = *(const h16x8*)(sp);
        h16x8 sv1 = *(const h16x8*)(sp + 8);
        h16x8 o80, o81;
#pragma unroll
        for (int i = 0; i < 8; i++) {
            o80[i] = (h16)(dd * ((float)acc0[i] + (float)sv0[i]));
            o81[i] = (h16)(dd * ((float)acc1[i] + (float)sv1[i]));
        }
        h16* np = nxt + (size_t)node * 64 + q * 16;
        *(h16x8*)(np) = o80;
        *(h16x8*)(np + 8) = o81;
    }
}

// ---------- 7. per-power linear: MFMA f16 ----------
__global__ void k_pout(const h16* __restrict__ cur, const h16* __restrict__ Wcf,
                       const float* __restrict__ bcv, const float* __restrict__ idis,
                       h16* __restrict__ hcat, int seg, int N) {
    __shared__ __align__(16) h16 Bf[2][4][64][8];   // 8 KB
    int tid = threadIdx.x;
    {
        int4* d = (int4*)&Bf[0][0][0][0];
        const int4* s4 = (const int4*)Wcf;
        for (int i = tid; i < 512; i += 256) d[i] = s4[i];
    }
    __syncthreads();
    int lane = tid & 63, quad = lane >> 4, m15 = lane & 15;
    float bcol[4];
#pragma unroll
    for (int t = 0; t < 4; t++) bcol[t] = bcv[t * 16 + m15];
    int wave = blockIdx.x * 4 + (tid >> 6);
    int nwave = gridDim.x * 4;
    int ntile = (N + 15) >> 4;
    for (int tile = wave; tile < ntile; tile += nwave) {
        int m0 = tile << 4;
        int mrow = m0 + m15; if (mrow >= N) mrow = N - 1;
        f32x4 acc[4];
#pragma unroll
        for (int t = 0; t < 4; t++)
#pragma unroll
            for (int r = 0; r < 4; r++) acc[t][r] = 0.0f;
#pragma unroll
        for (int c = 0; c < 2; c++) {
            h16x8 a = *(const h16x8*)(cur + (size_t)mrow * 64 + c * 32 + quad * 8);
#pragma unroll
            for (int t = 0; t < 4; t++) {
                h16x8 b = *(const h16x8*)(&Bf[c][t][lane][0]);
                acc[t] = __builtin_amdgcn_mfma_f32_16x16x32_f16(a, b, acc[t], 0, 0, 0);
            }
        }
#pragma unroll
        for (int r = 0; r < 4; r++) {
            int node = m0 + quad * 4 + r;
            if (node < N) {
                float di = idis[node];
#pragma unroll
                for (int t = 0; t < 4; t++)
                    hcat[(size_t)node * 192 + seg * 64 + t * 16 + m15] =
                        (h16)(bcol[t] + di * acc[t][r]);
            }
        }
    }
}

// ---------- 8. out = LN(gelu(hcat)) @ W2 + b2 ; MFMA f16, LN fused ----------
__global__ void k_fin(const h16* __restrict__ hcat, const h16* __restrict__ W2f,
                      const float* __restrict__ b2v, const float2* __restrict__ GBv,
                      void* __restrict__ out, const int* __restrict__ flag, int N) {
    __shared__ __align__(16) h16 Bf[6][3][64][8];   // 18 KB
    __shared__ float2 GBs[192];
    __shared__ __align__(16) h16 Y[4][16][200];     // raw gelu, per-wave
    int isbf = *flag;
    int tid = threadIdx.x;
    {
        int4* d = (int4*)&Bf[0][0][0][0];
        const int4* s4 = (const int4*)W2f;
        for (int i = tid; i < 1152; i += 256) d[i] = s4[i];
    }
    for (int i = tid; i < 192; i += 256) GBs[i] = GBv[i];
    __syncthreads();
    int wv = tid >> 6;
    int lane = tid & 63, quad = lane >> 4, m15 = lane & 15;
    float b2c[3];
#pragma unroll
    for (int t = 0; t < 3; t++) {
        int col = t * 16 + m15;
        b2c[t] = (col < 40) ? b2v[col] : 0.0f;
    }
    int wave = blockIdx.x * 4 + wv;
    int nwave = gridDim.x * 4;
    int ntile = (N + 15) >> 4;
    for (int tile = wave; tile < ntile; tile += nwave) {
        int m0 = tile << 4;
        int mrow = m0 + m15; if (mrow >= N) mrow = N - 1;
        const h16* hp = hcat + (size_t)mrow * 192 + quad * 48;
        float s = 0.0f, q = 0.0f;
#pragma unroll
        for (int u = 0; u < 6; u++) {
            h16x8 vv = *(const h16x8*)(hp + u * 8);
            h16x8 gv;
#pragma unroll
            for (int j = 0; j < 8; j++) {
                float g = gelu_fast((float)vv[j]);
                gv[j] = (h16)g;
                s += g; q += g * g;
            }
            *(h16x8*)(&Y[wv][m15][quad * 48 + u * 8]) = gv;
        }
        s += __shfl_xor(s, 16, 64); s += __shfl_xor(s, 32, 64);
        q += __shfl_xor(q, 16, 64); q += __shfl_xor(q, 32, 64);
        float mu = s * (1.0f / 192.0f);
        float var = q * (1.0f / 192.0f) - mu * mu;
        float rs = rsqrtf(var + LN_EPS);
        asm volatile("s_waitcnt lgkmcnt(0)" ::: "memory");   // cross-lane LDS RAW
        f32x4 acc[3];
#pragma unroll
        for (int t = 0; t < 3; t++)
#pragma unroll
            for (int r = 0; r < 4; r++) acc[t][r] = 0.0f;
#pragma unroll
        for (int c = 0; c < 6; c++) {
            h16x8 raw = *(const h16x8*)(&Y[wv][m15][c * 32 + quad * 8]);
            h16x8 a;
#pragma unroll
            for (int j = 0; j < 8; j++) {
                int k = c * 32 + quad * 8 + j;
                float2 gb = GBs[k];
                a[j] = (h16)(((float)raw[j] - mu) * rs * gb.x + gb.y);
            }
#pragma unroll
            for (int t = 0; t < 3; t++) {
                h16x8 b = *(const h16x8*)(&Bf[c][t][lane][0]);
                acc[t] = __builtin_amdgcn_mfma_f32_16x16x32_f16(a, b, acc[t], 0, 0, 0);
            }
        }
        asm volatile("" ::: "memory");
#pragma unroll
        for (int r = 0; r < 4; r++) {
            int node = m0 + quad * 4 + r;
            if (node < N) {
#pragma unroll
                for (int t = 0; t < 3; t++) {
                    int col = t * 16 + m15;
                    if (col < 40) {
                        float o = acc[t][r] + b2c[t];
                        if (isbf) ((unsigned short*)out)[(size_t)node * 40 + col] = f2bf(o);
                        else      ((float*)out)[(size_t)node * 40 + col] = o;
                    }
                }
            }
        }
    }
}

extern "C" void kernel_launch(void* const* d_in, const int* in_sizes, int n_in,
                              void* d_out, int out_size, void* d_ws, size_t ws_size,
                              hipStream_t stream) {
    const int IN = 128, HID = 64;
    const int N = in_sizes[0] / IN;        // 100000
    const int E = in_sizes[1] / 2;         // 3200000
    const int NB = (N + 511) >> 9;         // 196 dst-buckets
    const int chunk = (((E + NBLK - 1) / NBLK) + 3) & ~3;   // 4-aligned for int4 reads

    const void* x   = d_in[0];
    const int*  ei  = (const int*)d_in[1];
    const void* W1  = d_in[2];
    const void* b1  = d_in[3];
    const void* Wc  = d_in[4];
    const void* bc  = d_in[5];
    const void* W2  = d_in[6];
    const void* b2  = d_in[7];
    const void* g1  = d_in[8];
    const void* be1 = d_in[9];
    const void* g2  = d_in[10];
    const void* be2 = d_in[11];

    char* ws = (char*)d_ws;
    size_t off = 0;
    auto take = [&](size_t bytes) -> char* {
        char* p = ws + off;
        off = (off + bytes + 255) & ~(size_t)255;
        return p;
    };
    int*   flag  = (int*)take(256);
    int*   bcnt  = (int*)take(NBMAX * 4);
    int*   bbase = (int*)take((NBMAX + 1) * 4);
    float* dis   = (float*)take((size_t)N * 4);
    float* d2    = (float*)take((size_t)N * 4);
    float* idis  = (float*)take((size_t)N * 4);
    int*   offv  = (int*)take((size_t)(N + 1) * 4);
    int*   csr   = (int*)take((size_t)E * 4);
    // stg (E*4B, dead after k_build2) overlays hcat (N*384B, written later)
    size_t unionSz = (size_t)E * 4 > (size_t)N * 384 ? (size_t)E * 4 : (size_t)N * 384;
    char*  uni   = take(unionSz);
    unsigned* stg = (unsigned*)uni;
    h16*   hcat  = (h16*)uni;
    h16*   hA    = (h16*)take((size_t)N * HID * 2);
    h16*   hB    = (h16*)take((size_t)N * HID * 2);
    short* W1f  = (short*)take(16384);
    h16*   Wcf  = (h16*)take(24576);
    h16*   W2f  = (h16*)take(18432);
    float* vecs = (float*)take(2048);
    float2* GBv = (float2*)take(1536);
    // cnts/base (1 MB each) overlay csr: consumed before k_build2 writes csr.
    int*   cnts  = csr;
    int*   base  = csr + (size_t)NBLK * NBMAX;

    const int* srcp = ei;
    const int* dstp = ei + E;
    int gNode = (N + 7) / 8;
    int gDense = 1563;

    k_prep<<<6, 256, 0, stream>>>(W1, b1, g1, be1, Wc, bc, W2, b2, g2, be2, flag,
                                  bcnt, W1f, Wcf, W2f, vecs, GBv);
    k_bcnt<<<NBLK, 256, 0, stream>>>(dstp, bcnt, cnts, E, chunk);
    k_colscan<<<NB, 256, 0, stream>>>(bcnt, cnts, bbase, base, NB);
    if (chunk <= CHCAP)
        k_bin_sort<<<NBLK, 256, 0, stream>>>(srcp, dstp, base, cnts, stg, E, chunk);
    else
        k_bin<<<NBLK, 256, 0, stream>>>(srcp, dstp, base, stg, E, chunk);
    k_build2<<<NB, 512, 0, stream>>>(stg, bbase, offv, dis, d2, idis, csr, N, E, NB);

    k_in<<<gDense, 256, 0, stream>>>(x, W1f, vecs, dis, hA, flag, N);
    h16* cur = hA; h16* nxt = hB;
    int seg = 0;
    for (int j = 1; j <= 10; j++) {
        k_prop<<<gNode, 512, 0, stream>>>(cur, nxt, offv, csr, d2, N);
        h16* tmp = cur; cur = nxt; nxt = tmp;
        if (j == 6 || j == 8 || j == 10) {
            k_pout<<<gDense, 256, 0, stream>>>(cur, Wcf + (size_t)seg * 4096,
                                               vecs + 192 + seg * 64, idis,
                                               hcat, seg, N);
            seg++;
        }
    }
    k_fin<<<gDense, 256, 0, stream>>>(hcat, W2f, vecs + 384, GBv, d_out, flag, N);
}